// Round 7
// baseline (3464.359 us; speedup 1.0000x reference)
//
#include <hip/hip_runtime.h>

#define N_NODES 5000
#define N_EDGES 20000
#define B_GRAPHS 64
#define DD 64
#define HID 128
#define EDGE_FEAT 5
#define KTOT 8256   // 8192 + 64 bias rows
#define KY_SPLIT 8
#define KCHUNK 1032 // KTOT / KY_SPLIT

typedef float f32x4 __attribute__((ext_vector_type(4)));

__device__ __forceinline__ float sigf(float x) { return 1.f / (1.f + expf(-x)); }

// -------------------- lin0: h = relu(x @ W + b) --------------------
__global__ void k_lin0(const float* __restrict__ x, const float* __restrict__ w,
                       const float* __restrict__ b, float* __restrict__ h) {
  __shared__ float xs[64];
  int n = blockIdx.x, j = threadIdx.x;
  xs[j] = x[n * 64 + j];
  __syncthreads();
  float acc = b[j];
#pragma unroll
  for (int i = 0; i < 64; ++i) acc += xs[i] * w[i * 64 + j];
  h[n * 64 + j] = fmaxf(acc, 0.f);
}

// -------------------- deg (atomic count) --------------------
__global__ void k_deg(const int* __restrict__ dst, float* __restrict__ deg) {
  int e = blockIdx.x * 256 + threadIdx.x;
  if (e < N_EDGES) atomicAdd(&deg[dst[e]], 1.0f);
}

// -------------------- graph boundaries in sorted batch --------------------
__global__ void k_bounds(const int* __restrict__ batch, int* __restrict__ start) {
  int g = threadIdx.x;
  if (g > B_GRAPHS) return;
  int lo = 0, hi = N_NODES;
  while (lo < hi) { int mid = (lo + hi) >> 1; if (batch[mid] < g) lo = mid + 1; else hi = mid; }
  start[g] = lo;
}

// -------------------- fused msg (VALU; r1 recomputed in-block) ----------
// msg[e][o] = sum_{kp<8192} (r1[e][kp>>6]*h[src[e]][kp&63]) * w2[kp*64+o]
//           + sum_i h[src[e]][i] * b2[i*64+o]
__global__ __launch_bounds__(256) void k_msgv(const int* __restrict__ src,
                                              const int* __restrict__ dst,
                                              const float* __restrict__ h,
                                              const float* __restrict__ ea,
                                              const float* __restrict__ w1,
                                              const float* __restrict__ b1,
                                              const float* __restrict__ w2,
                                              const float* __restrict__ b2,
                                              float* __restrict__ agg) {
  __shared__ float hs[64][68];
  __shared__ float r1s[64][132];   // [128] = 1.0 for bias region
  __shared__ float w1s[EDGE_FEAT][HID];
  __shared__ float b1s[HID];
  __shared__ float eas[64][EDGE_FEAT];
  __shared__ int dsts[64];

  int bm = blockIdx.x, ky = blockIdx.y;
  int t = threadIdx.x;
  int wave = t >> 6, lane = t & 63;

  // ---- stage inputs ----
  if (t < HID) b1s[t] = b1[t];
  for (int i = t; i < EDGE_FEAT * HID; i += 256) w1s[i / HID][i % HID] = w1[i];
  {
    int r = t >> 2, qp = t & 3;
    int e = bm * 64 + r;
    if (t < 64) dsts[t] = (bm * 64 + t < N_EDGES) ? dst[bm * 64 + t] : -1;
    if (e < N_EDGES) {
      int s = src[e];
#pragma unroll
      for (int i = 0; i < 16; ++i) hs[r][qp * 16 + i] = h[(size_t)s * 64 + qp * 16 + i];
      if (qp == 0) {
#pragma unroll
        for (int k = 0; k < EDGE_FEAT; ++k) eas[r][k] = ea[(size_t)e * EDGE_FEAT + k];
      }
    } else {
#pragma unroll
      for (int i = 0; i < 16; ++i) hs[r][qp * 16 + i] = 0.f;
      if (qp == 0) {
#pragma unroll
        for (int k = 0; k < EDGE_FEAT; ++k) eas[r][k] = 0.f;
      }
    }
  }
  __syncthreads();

  // ---- recompute r1 rows ----
  for (int idx = t; idx < 64 * HID; idx += 256) {
    int rr = idx >> 7, c = idx & 127;
    float acc = b1s[c];
#pragma unroll
    for (int k = 0; k < EDGE_FEAT; ++k) acc += eas[rr][k] * w1s[k][c];
    r1s[rr][c] = fmaxf(acc, 0.f);
  }
  if (t < 64) r1s[t][128] = 1.0f;
  __syncthreads();

  int row0 = wave * 16 + (lane >> 4) * 4;
  int colb = lane & 15;

  float acc[4][4];
#pragma unroll
  for (int ct = 0; ct < 4; ++ct)
#pragma unroll
    for (int r = 0; r < 4; ++r) acc[ct][r] = 0.f;

  int k0 = ky * KCHUNK, k1 = k0 + KCHUNK;
  for (int kp = k0; kp < k1; ++kp) {
    int kap = kp >> 6, ii = kp & 63;
    const float* Bp = (kp < 8192) ? (w2 + (size_t)kp * 64)
                                  : (b2 + (size_t)(kp - 8192) * 64);
    float bv[4];
#pragma unroll
    for (int ct = 0; ct < 4; ++ct) bv[ct] = Bp[ct * 16 + colb];
#pragma unroll
    for (int r = 0; r < 4; ++r) {
      float a = r1s[row0 + r][kap] * hs[row0 + r][ii];
#pragma unroll
      for (int ct = 0; ct < 4; ++ct) acc[ct][r] += a * bv[ct];
    }
  }

  // ---- scatter ----
#pragma unroll
  for (int ct = 0; ct < 4; ++ct) {
    int col = ct * 16 + colb;
#pragma unroll
    for (int r = 0; r < 4; ++r) {
      int dd = dsts[row0 + r];
      if (dd >= 0) atomicAdd(&agg[(size_t)dd * 64 + col], acc[ct][r]);
    }
  }
}

// -------------------- GRU step (includes m = relu(agg/deg + conv_b)) ----------
__global__ __launch_bounds__(192) void k_gru(const float* __restrict__ agg, const float* __restrict__ deg,
                                             const float* __restrict__ conv_b,
                                             const float* __restrict__ wih, const float* __restrict__ whh,
                                             const float* __restrict__ bih, const float* __restrict__ bhh,
                                             float* __restrict__ h) {
  __shared__ float m[64], hr[64], gi[192], gh[192];
  int n = blockIdx.x, t = threadIdx.x;
  if (t < 64) {
    float dg = fmaxf(deg[n], 1.0f);
    m[t] = fmaxf(agg[n * 64 + t] / dg + conv_b[t], 0.f);
    hr[t] = h[n * 64 + t];
  }
  __syncthreads();
  float accI = bih[t], accH = bhh[t];
#pragma unroll 8
  for (int j = 0; j < 64; ++j) {
    accI += m[j] * wih[t * 64 + j];
    accH += hr[j] * whh[t * 64 + j];
  }
  gi[t] = accI; gh[t] = accH;
  __syncthreads();
  if (t < 64) {
    float r = sigf(gi[t] + gh[t]);
    float z = sigf(gi[64 + t] + gh[64 + t]);
    float nn = tanhf(gi[128 + t] + r * gh[128 + t]);
    h[n * 64 + t] = (1.f - z) * nn + z * hr[t];
  }
}

// -------------------- Set2Set LSTM step --------------------
__global__ void k_lstm(const float* __restrict__ wih, const float* __restrict__ whh,
                       const float* __restrict__ bih, const float* __restrict__ bhh,
                       const float* __restrict__ qstar, float* __restrict__ hh,
                       float* __restrict__ cc) {
  __shared__ float qs[128], hs[64];
  int b = blockIdx.x, j = threadIdx.x;
  qs[j] = qstar[b * 128 + j];
  qs[64 + j] = qstar[b * 128 + 64 + j];
  hs[j] = hh[b * 64 + j];
  __syncthreads();
  float g4[4];
#pragma unroll
  for (int g = 0; g < 4; ++g) {
    int k = g * 64 + j;
    float acc = bih[k] + bhh[k];
    for (int t2 = 0; t2 < 128; ++t2) acc += qs[t2] * wih[k * 128 + t2];
    for (int t2 = 0; t2 < 64; ++t2) acc += hs[t2] * whh[k * 64 + t2];
    g4[g] = acc;
  }
  float c_new = sigf(g4[1]) * cc[b * 64 + j] + sigf(g4[0]) * tanhf(g4[2]);
  float h_new = sigf(g4[3]) * tanhf(c_new);
  cc[b * 64 + j] = c_new;
  hh[b * 64 + j] = h_new;
}

// -------------------- e[i] = dot(feat[i], hh[batch[i]]) --------------------
__global__ void k_dot(const float* __restrict__ h, const int* __restrict__ batch,
                      const float* __restrict__ hh, float* __restrict__ e) {
  int wave = threadIdx.x >> 6, lane = threadIdx.x & 63;
  int n = blockIdx.x * 4 + wave;
  if (n >= N_NODES) return;
  int b = batch[n];
  float v = h[n * 64 + lane] * hh[b * 64 + lane];
#pragma unroll
  for (int off = 32; off > 0; off >>= 1) v += __shfl_down(v, off, 64);
  if (lane == 0) e[n] = v;
}

// -------------------- per-graph softmax pool + q_star write --------------------
__global__ __launch_bounds__(256) void k_pool(const float* __restrict__ e, const float* __restrict__ feat,
                                              const int* __restrict__ start, const float* __restrict__ hh,
                                              float* __restrict__ qstar) {
  __shared__ float red[256];
  __shared__ float part[4][64];
  __shared__ float s_emax, s_den;
  int g = blockIdx.x, t = threadIdx.x;
  int s0 = start[g], s1 = start[g + 1];
  if (t < 64) qstar[g * 128 + t] = hh[g * 64 + t];
  if (s0 >= s1) { if (t < 64) qstar[g * 128 + 64 + t] = 0.f; return; }

  float mx = -1e30f;
  for (int i = s0 + t; i < s1; i += 256) mx = fmaxf(mx, e[i]);
  red[t] = mx; __syncthreads();
  for (int off = 128; off; off >>= 1) { if (t < off) red[t] = fmaxf(red[t], red[t + off]); __syncthreads(); }
  if (t == 0) s_emax = red[0];
  __syncthreads();
  float emax = s_emax;

  float sm = 0.f;
  for (int i = s0 + t; i < s1; i += 256) sm += expf(e[i] - emax);
  red[t] = sm; __syncthreads();
  for (int off = 128; off; off >>= 1) { if (t < off) red[t] += red[t + off]; __syncthreads(); }
  if (t == 0) s_den = red[0];
  __syncthreads();
  float den = s_den;

  int o = t & 63, grp = t >> 6;
  float acc = 0.f;
  for (int i = s0 + grp; i < s1; i += 4) {
    float a = expf(e[i] - emax) / den;
    acc += a * feat[i * 64 + o];
  }
  part[grp][o] = acc; __syncthreads();
  if (t < 64) qstar[g * 128 + 64 + t] = part[0][t] + part[1][t] + part[2][t] + part[3][t];
}

// -------------------- output: [q_star (8192) | feat (320000)] as FLOAT32 ----------
__global__ void k_out(const float* __restrict__ qstar, const float* __restrict__ h,
                      float* __restrict__ out) {
  int i = blockIdx.x * 256 + threadIdx.x;
  if (i < B_GRAPHS * 128) out[i] = qstar[i];
  else out[i] = h[i - B_GRAPHS * 128];
}

extern "C" void kernel_launch(void* const* d_in, const int* in_sizes, int n_in,
                              void* d_out, int out_size, void* d_ws, size_t ws_size,
                              hipStream_t stream) {
  (void)in_sizes; (void)n_in; (void)out_size; (void)ws_size;
  const float* x        = (const float*)d_in[0];
  const int*   ei       = (const int*)d_in[1];
  const int*   batch    = (const int*)d_in[2];
  const float* ea       = (const float*)d_in[3];
  const float* lin0_w   = (const float*)d_in[4];
  const float* lin0_b   = (const float*)d_in[5];
  const float* nn_w1    = (const float*)d_in[6];
  const float* nn_b1    = (const float*)d_in[7];
  const float* nn_w2    = (const float*)d_in[8];
  const float* nn_b2    = (const float*)d_in[9];
  const float* conv_b   = (const float*)d_in[10];
  const float* gru_w_ih = (const float*)d_in[11];
  const float* gru_w_hh = (const float*)d_in[12];
  const float* gru_b_ih = (const float*)d_in[13];
  const float* gru_b_hh = (const float*)d_in[14];
  const float* lstm_w_ih= (const float*)d_in[15];
  const float* lstm_w_hh= (const float*)d_in[16];
  const float* lstm_b_ih= (const float*)d_in[17];
  const float* lstm_b_hh= (const float*)d_in[18];
  const int* srcp = ei;
  const int* dstp = ei + N_EDGES;

  char* ws = (char*)d_ws;
  size_t off = 0;
  auto alloc = [&](size_t bytes) { void* p = ws + off; off += (bytes + 255) & ~(size_t)255; return p; };
  float* h     = (float*)alloc((size_t)N_NODES * 64 * 4);
  float* agg   = (float*)alloc((size_t)N_NODES * 64 * 4);
  float* deg   = (float*)alloc((size_t)N_NODES * 4);
  float* ev    = (float*)alloc((size_t)N_NODES * 4);
  float* qstar = (float*)alloc((size_t)B_GRAPHS * 128 * 4);
  float* hhv   = (float*)alloc((size_t)B_GRAPHS * 64 * 4);
  float* ccv   = (float*)alloc((size_t)B_GRAPHS * 64 * 4);
  int*   startv= (int*)alloc(65 * 4);

  hipMemsetAsync(deg, 0, (size_t)N_NODES * 4, stream);
  hipMemsetAsync(qstar, 0, (size_t)B_GRAPHS * 128 * 4, stream);
  hipMemsetAsync(hhv, 0, (size_t)B_GRAPHS * 64 * 4, stream);
  hipMemsetAsync(ccv, 0, (size_t)B_GRAPHS * 64 * 4, stream);

  k_lin0<<<N_NODES, 64, 0, stream>>>(x, lin0_w, lin0_b, h);
  k_deg<<<(N_EDGES + 255) / 256, 256, 0, stream>>>(dstp, deg);
  k_bounds<<<1, 128, 0, stream>>>(batch, startv);

  for (int it = 0; it < 3; ++it) {
    hipMemsetAsync(agg, 0, (size_t)N_NODES * 64 * 4, stream);
    k_msgv<<<dim3(313, KY_SPLIT), 256, 0, stream>>>(srcp, dstp, h, ea, nn_w1, nn_b1,
                                                    nn_w2, nn_b2, agg);
    k_gru<<<N_NODES, 192, 0, stream>>>(agg, deg, conv_b, gru_w_ih, gru_w_hh,
                                       gru_b_ih, gru_b_hh, h);
  }

  for (int it = 0; it < 3; ++it) {
    k_lstm<<<B_GRAPHS, 64, 0, stream>>>(lstm_w_ih, lstm_w_hh, lstm_b_ih, lstm_b_hh,
                                        qstar, hhv, ccv);
    k_dot<<<(N_NODES + 3) / 4, 256, 0, stream>>>(h, batch, hhv, ev);
    k_pool<<<B_GRAPHS, 256, 0, stream>>>(ev, h, startv, hhv, qstar);
  }

  k_out<<<(B_GRAPHS * 128 + N_NODES * 64) / 256, 256, 0, stream>>>(qstar, h, (float*)d_out);
}

// Round 8
// 916.780 us; speedup vs baseline: 3.7788x; 3.7788x over previous
//
#include <hip/hip_runtime.h>

#define N_NODES 5000
#define N_EDGES 20000
#define B_GRAPHS 64
#define DD 64
#define HID 128
#define EDGE_FEAT 5
#define KTOT 8256   // 8192 + 64 bias cols
#define GSTRIDE 8256
#define KY_SPLIT 8
#define KCHUNK 1032 // KTOT / KY_SPLIT

typedef float f32x4 __attribute__((ext_vector_type(4)));

__device__ __forceinline__ float sigf(float x) { return 1.f / (1.f + expf(-x)); }

// -------------------- lin0: h = relu(x @ W + b) --------------------
__global__ void k_lin0(const float* __restrict__ x, const float* __restrict__ w,
                       const float* __restrict__ b, float* __restrict__ h) {
  __shared__ float xs[64];
  int n = blockIdx.x, j = threadIdx.x;
  xs[j] = x[n * 64 + j];
  __syncthreads();
  float acc = b[j];
#pragma unroll
  for (int i = 0; i < 64; ++i) acc += xs[i] * w[i * 64 + j];
  h[n * 64 + j] = fmaxf(acc, 0.f);
}

// -------------------- deg (atomic count) --------------------
__global__ void k_deg(const int* __restrict__ dst, float* __restrict__ deg) {
  int e = blockIdx.x * 256 + threadIdx.x;
  if (e < N_EDGES) atomicAdd(&deg[dst[e]], 1.0f);
}

// -------------------- graph boundaries in sorted batch --------------------
__global__ void k_bounds(const int* __restrict__ batch, int* __restrict__ start) {
  int g = threadIdx.x;
  if (g > B_GRAPHS) return;
  int lo = 0, hi = N_NODES;
  while (lo < hi) { int mid = (lo + hi) >> 1; if (batch[mid] < g) lo = mid + 1; else hi = mid; }
  start[g] = lo;
}

// -------------------- r1 = relu(edge_attr @ W1 + b1) --------------------
__global__ void k_r1(const float* __restrict__ ea, const float* __restrict__ w1,
                     const float* __restrict__ b1, float* __restrict__ r1) {
  __shared__ float a[EDGE_FEAT];
  int e = blockIdx.x, t = threadIdx.x;
  if (t < EDGE_FEAT) a[t] = ea[e * EDGE_FEAT + t];
  __syncthreads();
  float acc = b1[t];
#pragma unroll
  for (int k = 0; k < EDGE_FEAT; ++k) acc += a[k] * w1[k * HID + t];
  r1[e * HID + t] = fmaxf(acc, 0.f);
}

// -------------------- W2q[i][c]: c<8192 -> w2[(c>>6)*4096 + i*64 + (c&63)], else b2 ----
__global__ void k_w2p(const float* __restrict__ w2, const float* __restrict__ b2,
                      float* __restrict__ w2q) {
  int idx = blockIdx.x * 256 + threadIdx.x;
  if (idx >= 64 * KTOT) return;
  int i = idx / KTOT, c = idx - i * KTOT;
  w2q[idx] = (c < 8192) ? w2[(size_t)(c >> 6) * 4096 + i * 64 + (c & 63)]
                        : b2[i * 64 + (c - 8192)];
}

// -------------------- G = h @ W2q  (M=5000, K=64, N=8256; f32 VALU GEMM) ----------
// Tile 32 rows x 512 cols, 256 thr, each thread 32 rows x 2 cols.
__global__ __launch_bounds__(256) void k_G(const float* __restrict__ h,
                                           const float* __restrict__ w2q,
                                           float* __restrict__ G) {
  __shared__ float hs[32][64];
  int row0 = blockIdx.x * 32, c0 = blockIdx.y * 512;
  int t = threadIdx.x;
  int c = c0 + t * 2;

  for (int idx = t; idx < 32 * 64; idx += 256) {
    int r = idx >> 6, k = idx & 63;
    int row = row0 + r;
    hs[r][k] = (row < N_NODES) ? h[(size_t)row * 64 + k] : 0.f;
  }
  __syncthreads();

  float acc[64];
#pragma unroll
  for (int i = 0; i < 64; ++i) acc[i] = 0.f;

  bool inb = (c < KTOT);
  for (int k = 0; k < 64; ++k) {
    float w0 = 0.f, w1 = 0.f;
    if (inb) {
      w0 = w2q[(size_t)k * KTOT + c];
      w1 = w2q[(size_t)k * KTOT + c + 1];
    }
#pragma unroll
    for (int r = 0; r < 32; ++r) {
      float a = hs[r][k];
      acc[2 * r]     += a * w0;
      acc[2 * r + 1] += a * w1;
    }
  }

  if (inb) {
#pragma unroll
    for (int r = 0; r < 32; ++r) {
      int row = row0 + r;
      if (row < N_NODES) {
        G[(size_t)row * GSTRIDE + c]     = acc[2 * r];
        G[(size_t)row * GSTRIDE + c + 1] = acc[2 * r + 1];
      }
    }
  }
}

// -------------------- msg2: agg[dst] += r1[e] @ G2[src] + Hb[src] ----------
// One wave per edge; lane = output col o.
__global__ __launch_bounds__(256) void k_msg2(const int* __restrict__ src,
                                              const int* __restrict__ dst,
                                              const float* __restrict__ r1,
                                              const float* __restrict__ G,
                                              float* __restrict__ agg) {
  __shared__ float r1w[4][128];
  int w = threadIdx.x >> 6, l = threadIdx.x & 63;
  int e = blockIdx.x * 4 + w;
  int s = src[e], d = dst[e];

  r1w[w][l]      = r1[(size_t)e * HID + l];
  r1w[w][64 + l] = r1[(size_t)e * HID + 64 + l];
  // wave-local LDS write->read; compiler inserts lgkmcnt wait. No cross-wave sharing.
  __syncthreads();

  const float* Gs = G + (size_t)s * GSTRIDE;
  float acc = Gs[8192 + l];   // bias term Hb
#pragma unroll 8
  for (int kap = 0; kap < 128; ++kap)
    acc += r1w[w][kap] * Gs[kap * 64 + l];

  atomicAdd(&agg[(size_t)d * 64 + l], acc);
}

// -------------------- fallback: fused msg (VALU; r1 recomputed in-block) ----------
__global__ __launch_bounds__(256) void k_msgv(const int* __restrict__ src,
                                              const int* __restrict__ dst,
                                              const float* __restrict__ h,
                                              const float* __restrict__ ea,
                                              const float* __restrict__ w1,
                                              const float* __restrict__ b1,
                                              const float* __restrict__ w2,
                                              const float* __restrict__ b2,
                                              float* __restrict__ agg) {
  __shared__ float hs[64][68];
  __shared__ float r1s[64][132];
  __shared__ float w1s[EDGE_FEAT][HID];
  __shared__ float b1s[HID];
  __shared__ float eas[64][EDGE_FEAT];
  __shared__ int dsts[64];

  int bm = blockIdx.x, ky = blockIdx.y;
  int t = threadIdx.x;
  int wave = t >> 6, lane = t & 63;

  if (t < HID) b1s[t] = b1[t];
  for (int i = t; i < EDGE_FEAT * HID; i += 256) w1s[i / HID][i % HID] = w1[i];
  {
    int r = t >> 2, qp = t & 3;
    int e = bm * 64 + r;
    if (t < 64) dsts[t] = (bm * 64 + t < N_EDGES) ? dst[bm * 64 + t] : -1;
    if (e < N_EDGES) {
      int s = src[e];
#pragma unroll
      for (int i = 0; i < 16; ++i) hs[r][qp * 16 + i] = h[(size_t)s * 64 + qp * 16 + i];
      if (qp == 0)
#pragma unroll
        for (int k = 0; k < EDGE_FEAT; ++k) eas[r][k] = ea[(size_t)e * EDGE_FEAT + k];
    } else {
#pragma unroll
      for (int i = 0; i < 16; ++i) hs[r][qp * 16 + i] = 0.f;
      if (qp == 0)
#pragma unroll
        for (int k = 0; k < EDGE_FEAT; ++k) eas[r][k] = 0.f;
    }
  }
  __syncthreads();

  for (int idx = t; idx < 64 * HID; idx += 256) {
    int rr = idx >> 7, c = idx & 127;
    float acc = b1s[c];
#pragma unroll
    for (int k = 0; k < EDGE_FEAT; ++k) acc += eas[rr][k] * w1s[k][c];
    r1s[rr][c] = fmaxf(acc, 0.f);
  }
  if (t < 64) r1s[t][128] = 1.0f;
  __syncthreads();

  int row0 = wave * 16 + (lane >> 4) * 4;
  int colb = lane & 15;

  float acc[4][4];
#pragma unroll
  for (int ct = 0; ct < 4; ++ct)
#pragma unroll
    for (int r = 0; r < 4; ++r) acc[ct][r] = 0.f;

  int k0 = ky * KCHUNK, k1 = k0 + KCHUNK;
  for (int kp = k0; kp < k1; ++kp) {
    int kap = kp >> 6, ii = kp & 63;
    const float* Bp = (kp < 8192) ? (w2 + (size_t)kp * 64)
                                  : (b2 + (size_t)(kp - 8192) * 64);
    float bv[4];
#pragma unroll
    for (int ct = 0; ct < 4; ++ct) bv[ct] = Bp[ct * 16 + colb];
#pragma unroll
    for (int r = 0; r < 4; ++r) {
      float a = r1s[row0 + r][kap] * hs[row0 + r][ii];
#pragma unroll
      for (int ct = 0; ct < 4; ++ct) acc[ct][r] += a * bv[ct];
    }
  }

#pragma unroll
  for (int ct = 0; ct < 4; ++ct) {
    int col = ct * 16 + colb;
#pragma unroll
    for (int r = 0; r < 4; ++r) {
      int dd = dsts[row0 + r];
      if (dd >= 0) atomicAdd(&agg[(size_t)dd * 64 + col], acc[ct][r]);
    }
  }
}

// -------------------- GRU step (includes m = relu(agg/deg + conv_b)) ----------
__global__ __launch_bounds__(192) void k_gru(const float* __restrict__ agg, const float* __restrict__ deg,
                                             const float* __restrict__ conv_b,
                                             const float* __restrict__ wih, const float* __restrict__ whh,
                                             const float* __restrict__ bih, const float* __restrict__ bhh,
                                             float* __restrict__ h) {
  __shared__ float m[64], hr[64], gi[192], gh[192];
  int n = blockIdx.x, t = threadIdx.x;
  if (t < 64) {
    float dg = fmaxf(deg[n], 1.0f);
    m[t] = fmaxf(agg[n * 64 + t] / dg + conv_b[t], 0.f);
    hr[t] = h[n * 64 + t];
  }
  __syncthreads();
  float accI = bih[t], accH = bhh[t];
#pragma unroll 8
  for (int j = 0; j < 64; ++j) {
    accI += m[j] * wih[t * 64 + j];
    accH += hr[j] * whh[t * 64 + j];
  }
  gi[t] = accI; gh[t] = accH;
  __syncthreads();
  if (t < 64) {
    float r = sigf(gi[t] + gh[t]);
    float z = sigf(gi[64 + t] + gh[64 + t]);
    float nn = tanhf(gi[128 + t] + r * gh[128 + t]);
    h[n * 64 + t] = (1.f - z) * nn + z * hr[t];
  }
}

// -------------------- Set2Set LSTM step --------------------
__global__ void k_lstm(const float* __restrict__ wih, const float* __restrict__ whh,
                       const float* __restrict__ bih, const float* __restrict__ bhh,
                       const float* __restrict__ qstar, float* __restrict__ hh,
                       float* __restrict__ cc) {
  __shared__ float qs[128], hs[64];
  int b = blockIdx.x, j = threadIdx.x;
  qs[j] = qstar[b * 128 + j];
  qs[64 + j] = qstar[b * 128 + 64 + j];
  hs[j] = hh[b * 64 + j];
  __syncthreads();
  float g4[4];
#pragma unroll
  for (int g = 0; g < 4; ++g) {
    int k = g * 64 + j;
    float acc = bih[k] + bhh[k];
    for (int t2 = 0; t2 < 128; ++t2) acc += qs[t2] * wih[k * 128 + t2];
    for (int t2 = 0; t2 < 64; ++t2) acc += hs[t2] * whh[k * 64 + t2];
    g4[g] = acc;
  }
  float c_new = sigf(g4[1]) * cc[b * 64 + j] + sigf(g4[0]) * tanhf(g4[2]);
  float h_new = sigf(g4[3]) * tanhf(c_new);
  cc[b * 64 + j] = c_new;
  hh[b * 64 + j] = h_new;
}

// -------------------- e[i] = dot(feat[i], hh[batch[i]]) --------------------
__global__ void k_dot(const float* __restrict__ h, const int* __restrict__ batch,
                      const float* __restrict__ hh, float* __restrict__ e) {
  int wave = threadIdx.x >> 6, lane = threadIdx.x & 63;
  int n = blockIdx.x * 4 + wave;
  if (n >= N_NODES) return;
  int b = batch[n];
  float v = h[n * 64 + lane] * hh[b * 64 + lane];
#pragma unroll
  for (int off = 32; off > 0; off >>= 1) v += __shfl_down(v, off, 64);
  if (lane == 0) e[n] = v;
}

// -------------------- per-graph softmax pool + q_star write --------------------
__global__ __launch_bounds__(256) void k_pool(const float* __restrict__ e, const float* __restrict__ feat,
                                              const int* __restrict__ start, const float* __restrict__ hh,
                                              float* __restrict__ qstar) {
  __shared__ float red[256];
  __shared__ float part[4][64];
  __shared__ float s_emax, s_den;
  int g = blockIdx.x, t = threadIdx.x;
  int s0 = start[g], s1 = start[g + 1];
  if (t < 64) qstar[g * 128 + t] = hh[g * 64 + t];
  if (s0 >= s1) { if (t < 64) qstar[g * 128 + 64 + t] = 0.f; return; }

  float mx = -1e30f;
  for (int i = s0 + t; i < s1; i += 256) mx = fmaxf(mx, e[i]);
  red[t] = mx; __syncthreads();
  for (int off = 128; off; off >>= 1) { if (t < off) red[t] = fmaxf(red[t], red[t + off]); __syncthreads(); }
  if (t == 0) s_emax = red[0];
  __syncthreads();
  float emax = s_emax;

  float sm = 0.f;
  for (int i = s0 + t; i < s1; i += 256) sm += expf(e[i] - emax);
  red[t] = sm; __syncthreads();
  for (int off = 128; off; off >>= 1) { if (t < off) red[t] += red[t + off]; __syncthreads(); }
  if (t == 0) s_den = red[0];
  __syncthreads();
  float den = s_den;

  int o = t & 63, grp = t >> 6;
  float acc = 0.f;
  for (int i = s0 + grp; i < s1; i += 4) {
    float a = expf(e[i] - emax) / den;
    acc += a * feat[i * 64 + o];
  }
  part[grp][o] = acc; __syncthreads();
  if (t < 64) qstar[g * 128 + 64 + t] = part[0][t] + part[1][t] + part[2][t] + part[3][t];
}

// -------------------- output: [q_star (8192) | feat (320000)] as FLOAT32 ----------
__global__ void k_out(const float* __restrict__ qstar, const float* __restrict__ h,
                      float* __restrict__ out) {
  int i = blockIdx.x * 256 + threadIdx.x;
  if (i < B_GRAPHS * 128) out[i] = qstar[i];
  else out[i] = h[i - B_GRAPHS * 128];
}

extern "C" void kernel_launch(void* const* d_in, const int* in_sizes, int n_in,
                              void* d_out, int out_size, void* d_ws, size_t ws_size,
                              hipStream_t stream) {
  (void)in_sizes; (void)n_in; (void)out_size;
  const float* x        = (const float*)d_in[0];
  const int*   ei       = (const int*)d_in[1];
  const int*   batch    = (const int*)d_in[2];
  const float* ea       = (const float*)d_in[3];
  const float* lin0_w   = (const float*)d_in[4];
  const float* lin0_b   = (const float*)d_in[5];
  const float* nn_w1    = (const float*)d_in[6];
  const float* nn_b1    = (const float*)d_in[7];
  const float* nn_w2    = (const float*)d_in[8];
  const float* nn_b2    = (const float*)d_in[9];
  const float* conv_b   = (const float*)d_in[10];
  const float* gru_w_ih = (const float*)d_in[11];
  const float* gru_w_hh = (const float*)d_in[12];
  const float* gru_b_ih = (const float*)d_in[13];
  const float* gru_b_hh = (const float*)d_in[14];
  const float* lstm_w_ih= (const float*)d_in[15];
  const float* lstm_w_hh= (const float*)d_in[16];
  const float* lstm_b_ih= (const float*)d_in[17];
  const float* lstm_b_hh= (const float*)d_in[18];
  const int* srcp = ei;
  const int* dstp = ei + N_EDGES;

  char* ws = (char*)d_ws;
  size_t off = 0;
  auto alloc = [&](size_t bytes) { void* p = ws + off; off += (bytes + 255) & ~(size_t)255; return p; };
  float* h     = (float*)alloc((size_t)N_NODES * 64 * 4);
  float* agg   = (float*)alloc((size_t)N_NODES * 64 * 4);
  float* deg   = (float*)alloc((size_t)N_NODES * 4);
  float* ev    = (float*)alloc((size_t)N_NODES * 4);
  float* qstar = (float*)alloc((size_t)B_GRAPHS * 128 * 4);
  float* hhv   = (float*)alloc((size_t)B_GRAPHS * 64 * 4);
  float* ccv   = (float*)alloc((size_t)B_GRAPHS * 64 * 4);
  int*   startv= (int*)alloc(65 * 4);
  float* r1    = (float*)alloc((size_t)N_EDGES * HID * 4);          // 10.24 MB
  float* w2q   = (float*)alloc((size_t)64 * KTOT * 4);              // 2.11 MB
  float* G     = (float*)alloc((size_t)N_NODES * GSTRIDE * 4);      // 165.1 MB
  bool useG = (ws_size >= off);   // deterministic per capture

  hipMemsetAsync(deg, 0, (size_t)N_NODES * 4, stream);
  hipMemsetAsync(qstar, 0, (size_t)B_GRAPHS * 128 * 4, stream);
  hipMemsetAsync(hhv, 0, (size_t)B_GRAPHS * 64 * 4, stream);
  hipMemsetAsync(ccv, 0, (size_t)B_GRAPHS * 64 * 4, stream);

  k_lin0<<<N_NODES, 64, 0, stream>>>(x, lin0_w, lin0_b, h);
  k_deg<<<(N_EDGES + 255) / 256, 256, 0, stream>>>(dstp, deg);
  k_bounds<<<1, 128, 0, stream>>>(batch, startv);

  if (useG) {
    k_r1<<<N_EDGES, HID, 0, stream>>>(ea, nn_w1, nn_b1, r1);
    k_w2p<<<(64 * KTOT + 255) / 256, 256, 0, stream>>>(nn_w2, nn_b2, w2q);
    for (int it = 0; it < 3; ++it) {
      hipMemsetAsync(agg, 0, (size_t)N_NODES * 64 * 4, stream);
      k_G<<<dim3((N_NODES + 31) / 32, (KTOT + 511) / 512), 256, 0, stream>>>(h, w2q, G);
      k_msg2<<<N_EDGES / 4, 256, 0, stream>>>(srcp, dstp, r1, G, agg);
      k_gru<<<N_NODES, 192, 0, stream>>>(agg, deg, conv_b, gru_w_ih, gru_w_hh,
                                         gru_b_ih, gru_b_hh, h);
    }
  } else {
    for (int it = 0; it < 3; ++it) {
      hipMemsetAsync(agg, 0, (size_t)N_NODES * 64 * 4, stream);
      k_msgv<<<dim3(313, KY_SPLIT), 256, 0, stream>>>(srcp, dstp, h, ea, nn_w1, nn_b1,
                                                      nn_w2, nn_b2, agg);
      k_gru<<<N_NODES, 192, 0, stream>>>(agg, deg, conv_b, gru_w_ih, gru_w_hh,
                                         gru_b_ih, gru_b_hh, h);
    }
  }

  for (int it = 0; it < 3; ++it) {
    k_lstm<<<B_GRAPHS, 64, 0, stream>>>(lstm_w_ih, lstm_w_hh, lstm_b_ih, lstm_b_hh,
                                        qstar, hhv, ccv);
    k_dot<<<(N_NODES + 3) / 4, 256, 0, stream>>>(h, batch, hhv, ev);
    k_pool<<<B_GRAPHS, 256, 0, stream>>>(ev, h, startv, hhv, qstar);
  }

  k_out<<<(B_GRAPHS * 128 + N_NODES * 64) / 256, 256, 0, stream>>>(qstar, h, (float*)d_out);
}

// Round 9
// 551.302 us; speedup vs baseline: 6.2840x; 1.6629x over previous
//
#include <hip/hip_runtime.h>

#define N_NODES 5000
#define N_EDGES 20000
#define B_GRAPHS 64
#define DD 64
#define HID 128
#define EDGE_FEAT 5
#define KTOT 8256   // 8192 + 64 bias cols
#define GSTRIDE 8256
#define KY_SPLIT 8
#define KCHUNK 1032

typedef unsigned short u16;
typedef float f32x4 __attribute__((ext_vector_type(4)));
typedef u16 u16x8 __attribute__((ext_vector_type(8)));
typedef __bf16 bf16x8 __attribute__((ext_vector_type(8)));
union AB { u16x8 u; bf16x8 b; };

__device__ __forceinline__ float b2f(u16 u) {
  union { unsigned u32; float f; } v; v.u32 = ((unsigned)u) << 16; return v.f;
}
__device__ __forceinline__ u16 f2b(float f) {
  union { float f; unsigned u; } v; v.f = f;
  unsigned r = v.u + 0x7FFF + ((v.u >> 16) & 1);
  return (u16)(r >> 16);
}
__device__ __forceinline__ float sigf(float x) { return 1.f / (1.f + expf(-x)); }

// -------------------- lin0: h = relu(x @ W + b), 4 nodes/block --------------------
__global__ __launch_bounds__(256) void k_lin0(const float* __restrict__ x, const float* __restrict__ w,
                       const float* __restrict__ b, float* __restrict__ h) {
  __shared__ float xs[4][64];
  int wv = threadIdx.x >> 6, j = threadIdx.x & 63;
  int n = blockIdx.x * 4 + wv;
  if (n >= N_NODES) return;
  xs[wv][j] = x[(size_t)n * 64 + j];
  __syncthreads();
  float acc = b[j];
#pragma unroll
  for (int i = 0; i < 64; ++i) acc += xs[wv][i] * w[i * 64 + j];
  h[(size_t)n * 64 + j] = fmaxf(acc, 0.f);
}

// -------------------- deg (atomic count) --------------------
__global__ void k_deg(const int* __restrict__ dst, float* __restrict__ deg) {
  int e = blockIdx.x * 256 + threadIdx.x;
  if (e < N_EDGES) atomicAdd(&deg[dst[e]], 1.0f);
}

// -------------------- graph boundaries in sorted batch --------------------
__global__ void k_bounds(const int* __restrict__ batch, int* __restrict__ start) {
  int g = threadIdx.x;
  if (g > B_GRAPHS) return;
  int lo = 0, hi = N_NODES;
  while (lo < hi) { int mid = (lo + hi) >> 1; if (batch[mid] < g) lo = mid + 1; else hi = mid; }
  start[g] = lo;
}

// -------------------- r1 = relu(edge_attr @ W1 + b1) --------------------
__global__ void k_r1(const float* __restrict__ ea, const float* __restrict__ w1,
                     const float* __restrict__ b1, float* __restrict__ r1) {
  __shared__ float a[EDGE_FEAT];
  int e = blockIdx.x, t = threadIdx.x;
  if (t < EDGE_FEAT) a[t] = ea[e * EDGE_FEAT + t];
  __syncthreads();
  float acc = b1[t];
#pragma unroll
  for (int k = 0; k < EDGE_FEAT; ++k) acc += a[k] * w1[k * HID + t];
  r1[e * HID + t] = fmaxf(acc, 0.f);
}

// ---------- w2qT[c][i] = bf16(w2[c>>6][i*64 + (c&63)]), c<8192; else b2[i*64+(c-8192)] ----
__global__ void k_w2p(const float* __restrict__ w2, const float* __restrict__ b2,
                      u16* __restrict__ w2qT) {
  int idx = blockIdx.x * 256 + threadIdx.x;
  if (idx >= KTOT * 64) return;
  int c = idx >> 6, i = idx & 63;
  float v = (c < 8192) ? w2[(size_t)(c >> 6) * 4096 + i * 64 + (c & 63)]
                       : b2[i * 64 + (c - 8192)];
  w2qT[idx] = f2b(v);
}

// -------------------- G = h @ W2q via MFMA bf16; G stored bf16 --------------------
// Block: 64 rows x 256 cols, 4 waves (wave = 64-col strip). K=64 (2 ksteps of 32).
__global__ __launch_bounds__(256) void k_Gm(const float* __restrict__ h,
                                            const u16* __restrict__ w2qT,
                                            u16* __restrict__ G) {
  __shared__ u16 hsb[64][72];    // bf16 h tile, +8 pad
  __shared__ u16 outs[64][264];  // bf16 out tile, +8 pad
  int row0 = blockIdx.x * 64, c0 = blockIdx.y * 256;
  int t = threadIdx.x, w = t >> 6, lane = t & 63;

  {
    int r = t >> 2, qp = t & 3;
    int row = row0 + r;
#pragma unroll
    for (int i = 0; i < 16; ++i) {
      float v = (row < N_NODES) ? h[(size_t)row * 64 + qp * 16 + i] : 0.f;
      hsb[r][qp * 16 + i] = f2b(v);
    }
  }
  __syncthreads();

  f32x4 acc[4][4];
#pragma unroll
  for (int rt = 0; rt < 4; ++rt)
#pragma unroll
    for (int ct = 0; ct < 4; ++ct) acc[rt][ct] = (f32x4){0.f, 0.f, 0.f, 0.f};

  int colbase = c0 + w * 64;
#pragma unroll
  for (int ks = 0; ks < 2; ++ks) {
    int kb = ks * 32 + (lane >> 4) * 8;
    AB afr[4];
#pragma unroll
    for (int rt = 0; rt < 4; ++rt)
      afr[rt].u = *(const u16x8*)&hsb[rt * 16 + (lane & 15)][kb];
#pragma unroll
    for (int ct = 0; ct < 4; ++ct) {
      int c = colbase + ct * 16 + (lane & 15);
      AB bfr;
      if (c < KTOT) bfr.u = *(const u16x8*)(w2qT + (size_t)c * 64 + kb);
      else bfr.u = (u16x8){0, 0, 0, 0, 0, 0, 0, 0};
#pragma unroll
      for (int rt = 0; rt < 4; ++rt)
        acc[rt][ct] = __builtin_amdgcn_mfma_f32_16x16x32_bf16(afr[rt].b, bfr.b, acc[rt][ct], 0, 0, 0);
    }
  }

#pragma unroll
  for (int rt = 0; rt < 4; ++rt)
#pragma unroll
    for (int ct = 0; ct < 4; ++ct) {
      int lcol = w * 64 + ct * 16 + (lane & 15);
      int lrow0 = rt * 16 + (lane >> 4) * 4;
#pragma unroll
      for (int r = 0; r < 4; ++r) outs[lrow0 + r][lcol] = f2b(acc[rt][ct][r]);
    }
  __syncthreads();

  {
    int r = t >> 2, seg = t & 3;
    int row = row0 + r;
    if (row < N_NODES) {
#pragma unroll
      for (int i = 0; i < 8; ++i) {
        int c = seg * 64 + i * 8;
        int gc = c0 + c;
        if (gc < KTOT)
          *(u16x8*)(G + (size_t)row * GSTRIDE + gc) = *(const u16x8*)&outs[r][c];
      }
    }
  }
}

// -------------------- msg2: agg[dst] += r1[e] @ G[src] (+bias col) ----------
__global__ __launch_bounds__(256) void k_msg2(const int* __restrict__ src,
                                              const int* __restrict__ dst,
                                              const float* __restrict__ r1,
                                              const u16* __restrict__ G,
                                              float* __restrict__ agg) {
  __shared__ float r1w[4][128];
  int w = threadIdx.x >> 6, l = threadIdx.x & 63;
  int e = blockIdx.x * 4 + w;
  int s = src[e], d = dst[e];

  r1w[w][l]      = r1[(size_t)e * HID + l];
  r1w[w][64 + l] = r1[(size_t)e * HID + 64 + l];
  __syncthreads();

  const u16* Gs = G + (size_t)s * GSTRIDE;
  float acc = b2f(Gs[8192 + l]);
#pragma unroll 8
  for (int kap = 0; kap < 128; ++kap)
    acc += r1w[w][kap] * b2f(Gs[kap * 64 + l]);

  atomicAdd(&agg[(size_t)d * 64 + l], acc);
}

// -------------------- fallback: fused msg (VALU; r1 recomputed in-block) ----------
__global__ __launch_bounds__(256) void k_msgv(const int* __restrict__ src,
                                              const int* __restrict__ dst,
                                              const float* __restrict__ h,
                                              const float* __restrict__ ea,
                                              const float* __restrict__ w1,
                                              const float* __restrict__ b1,
                                              const float* __restrict__ w2,
                                              const float* __restrict__ b2,
                                              float* __restrict__ agg) {
  __shared__ float hs[64][68];
  __shared__ float r1s[64][132];
  __shared__ float w1s[EDGE_FEAT][HID];
  __shared__ float b1s[HID];
  __shared__ float eas[64][EDGE_FEAT];
  __shared__ int dsts[64];

  int bm = blockIdx.x, ky = blockIdx.y;
  int t = threadIdx.x;
  int wave = t >> 6, lane = t & 63;

  if (t < HID) b1s[t] = b1[t];
  for (int i = t; i < EDGE_FEAT * HID; i += 256) w1s[i / HID][i % HID] = w1[i];
  {
    int r = t >> 2, qp = t & 3;
    int e = bm * 64 + r;
    if (t < 64) dsts[t] = (bm * 64 + t < N_EDGES) ? dst[bm * 64 + t] : -1;
    if (e < N_EDGES) {
      int s = src[e];
#pragma unroll
      for (int i = 0; i < 16; ++i) hs[r][qp * 16 + i] = h[(size_t)s * 64 + qp * 16 + i];
      if (qp == 0)
#pragma unroll
        for (int k = 0; k < EDGE_FEAT; ++k) eas[r][k] = ea[(size_t)e * EDGE_FEAT + k];
    } else {
#pragma unroll
      for (int i = 0; i < 16; ++i) hs[r][qp * 16 + i] = 0.f;
      if (qp == 0)
#pragma unroll
        for (int k = 0; k < EDGE_FEAT; ++k) eas[r][k] = 0.f;
    }
  }
  __syncthreads();

  for (int idx = t; idx < 64 * HID; idx += 256) {
    int rr = idx >> 7, c = idx & 127;
    float acc = b1s[c];
#pragma unroll
    for (int k = 0; k < EDGE_FEAT; ++k) acc += eas[rr][k] * w1s[k][c];
    r1s[rr][c] = fmaxf(acc, 0.f);
  }
  if (t < 64) r1s[t][128] = 1.0f;
  __syncthreads();

  int row0 = wave * 16 + (lane >> 4) * 4;
  int colb = lane & 15;

  float acc[4][4];
#pragma unroll
  for (int ct = 0; ct < 4; ++ct)
#pragma unroll
    for (int r = 0; r < 4; ++r) acc[ct][r] = 0.f;

  int k0 = ky * KCHUNK, k1 = k0 + KCHUNK;
  for (int kp = k0; kp < k1; ++kp) {
    int kap = kp >> 6, ii = kp & 63;
    const float* Bp = (kp < 8192) ? (w2 + (size_t)kp * 64)
                                  : (b2 + (size_t)(kp - 8192) * 64);
    float bv[4];
#pragma unroll
    for (int ct = 0; ct < 4; ++ct) bv[ct] = Bp[ct * 16 + colb];
#pragma unroll
    for (int r = 0; r < 4; ++r) {
      float a = r1s[row0 + r][kap] * hs[row0 + r][ii];
#pragma unroll
      for (int ct = 0; ct < 4; ++ct) acc[ct][r] += a * bv[ct];
    }
  }

#pragma unroll
  for (int ct = 0; ct < 4; ++ct) {
    int col = ct * 16 + colb;
#pragma unroll
    for (int r = 0; r < 4; ++r) {
      int dd = dsts[row0 + r];
      if (dd >= 0) atomicAdd(&agg[(size_t)dd * 64 + col], acc[ct][r]);
    }
  }
}

// -------------------- GRU step (m = relu(agg/deg + conv_b)) ----------
__global__ __launch_bounds__(192) void k_gru(const float* __restrict__ agg, const float* __restrict__ deg,
                                             const float* __restrict__ conv_b,
                                             const float* __restrict__ wih, const float* __restrict__ whh,
                                             const float* __restrict__ bih, const float* __restrict__ bhh,
                                             float* __restrict__ h) {
  __shared__ float m[64], hr[64], gi[192], gh[192];
  int n = blockIdx.x, t = threadIdx.x;
  if (t < 64) {
    float dg = fmaxf(deg[n], 1.0f);
    m[t] = fmaxf(agg[n * 64 + t] / dg + conv_b[t], 0.f);
    hr[t] = h[n * 64 + t];
  }
  __syncthreads();
  float accI = bih[t], accH = bhh[t];
  const f32x4* wr = (const f32x4*)(wih + t * 64);
  const f32x4* hr4 = (const f32x4*)(whh + t * 64);
#pragma unroll
  for (int i = 0; i < 16; ++i) {
    f32x4 v = wr[i];
    accI += m[4 * i] * v.x + m[4 * i + 1] * v.y + m[4 * i + 2] * v.z + m[4 * i + 3] * v.w;
    f32x4 u = hr4[i];
    accH += hr[4 * i] * u.x + hr[4 * i + 1] * u.y + hr[4 * i + 2] * u.z + hr[4 * i + 3] * u.w;
  }
  gi[t] = accI; gh[t] = accH;
  __syncthreads();
  if (t < 64) {
    float r = sigf(gi[t] + gh[t]);
    float z = sigf(gi[64 + t] + gh[64 + t]);
    float nn = tanhf(gi[128 + t] + r * gh[128 + t]);
    h[n * 64 + t] = (1.f - z) * nn + z * hr[t];
  }
}

// -------------------- fused Set2Set: 1 block per graph, 3 steps in-kernel ----------
__global__ __launch_bounds__(256) void k_s2s(const float* __restrict__ wih, const float* __restrict__ whh,
                                             const float* __restrict__ bih, const float* __restrict__ bhh,
                                             const float* __restrict__ feat, const int* __restrict__ start,
                                             float* __restrict__ ev, float* __restrict__ outq) {
  __shared__ float qs[128], hhs[64], ccs[64], gates[256], part[4][64], redm[4];
  int g = blockIdx.x, t = threadIdx.x, w = t >> 6, l = t & 63;
  int s0 = start[g], s1 = start[g + 1];
  if (t < 128) qs[t] = 0.f;
  if (t < 64) { hhs[t] = 0.f; ccs[t] = 0.f; }
  __syncthreads();

  for (int step = 0; step < 3; ++step) {
    // LSTM gates: thread t = gate unit
    {
      float acc = bih[t] + bhh[t];
      const f32x4* wr = (const f32x4*)(wih + (size_t)t * 128);
#pragma unroll
      for (int i = 0; i < 32; ++i) {
        f32x4 v = wr[i];
        acc += qs[4 * i] * v.x + qs[4 * i + 1] * v.y + qs[4 * i + 2] * v.z + qs[4 * i + 3] * v.w;
      }
      const f32x4* hr = (const f32x4*)(whh + (size_t)t * 64);
#pragma unroll
      for (int i = 0; i < 16; ++i) {
        f32x4 v = hr[i];
        acc += hhs[4 * i] * v.x + hhs[4 * i + 1] * v.y + hhs[4 * i + 2] * v.z + hhs[4 * i + 3] * v.w;
      }
      gates[t] = acc;
    }
    __syncthreads();
    if (t < 64) {
      float c_new = sigf(gates[64 + t]) * ccs[t] + sigf(gates[t]) * tanhf(gates[128 + t]);
      hhs[t] = sigf(gates[192 + t]) * tanhf(c_new);
      ccs[t] = c_new;
      qs[t] = hhs[t];
    }
    __syncthreads();

    // attention scores + max
    float mw = -1e30f;
    for (int n = s0 + w; n < s1; n += 4) {
      float v = feat[(size_t)n * 64 + l] * hhs[l];
#pragma unroll
      for (int off = 32; off; off >>= 1) v += __shfl_xor(v, off, 64);
      if (l == 0) ev[n] = v;
      mw = fmaxf(mw, v);
    }
    if (l == 0) redm[w] = mw;
    __syncthreads();
    float emax = fmaxf(fmaxf(redm[0], redm[1]), fmaxf(redm[2], redm[3]));
    // denominator
    float sd = 0.f;
    for (int n = s0 + t; n < s1; n += 256) sd += expf(ev[n] - emax);
    gates[t] = sd; __syncthreads();
    for (int off = 128; off; off >>= 1) { if (t < off) gates[t] += gates[t + off]; __syncthreads(); }
    float den = gates[0];
    __syncthreads();
    // weighted pool
    float pacc = 0.f;
    for (int n = s0 + w; n < s1; n += 4) {
      float a = expf(ev[n] - emax) / den;
      pacc += a * feat[(size_t)n * 64 + l];
    }
    part[w][l] = pacc; __syncthreads();
    if (t < 64) qs[64 + t] = part[0][t] + part[1][t] + part[2][t] + part[3][t];
    __syncthreads();
  }
  if (t < 128) outq[g * 128 + t] = qs[t];
}

// -------------------- feat part of output --------------------
__global__ void k_outf(const float* __restrict__ h, float* __restrict__ out) {
  int i = blockIdx.x * 256 + threadIdx.x;
  if (i < N_NODES * 64) out[B_GRAPHS * 128 + i] = h[i];
}

extern "C" void kernel_launch(void* const* d_in, const int* in_sizes, int n_in,
                              void* d_out, int out_size, void* d_ws, size_t ws_size,
                              hipStream_t stream) {
  (void)in_sizes; (void)n_in; (void)out_size;
  const float* x        = (const float*)d_in[0];
  const int*   ei       = (const int*)d_in[1];
  const int*   batch    = (const int*)d_in[2];
  const float* ea       = (const float*)d_in[3];
  const float* lin0_w   = (const float*)d_in[4];
  const float* lin0_b   = (const float*)d_in[5];
  const float* nn_w1    = (const float*)d_in[6];
  const float* nn_b1    = (const float*)d_in[7];
  const float* nn_w2    = (const float*)d_in[8];
  const float* nn_b2    = (const float*)d_in[9];
  const float* conv_b   = (const float*)d_in[10];
  const float* gru_w_ih = (const float*)d_in[11];
  const float* gru_w_hh = (const float*)d_in[12];
  const float* gru_b_ih = (const float*)d_in[13];
  const float* gru_b_hh = (const float*)d_in[14];
  const float* lstm_w_ih= (const float*)d_in[15];
  const float* lstm_w_hh= (const float*)d_in[16];
  const float* lstm_b_ih= (const float*)d_in[17];
  const float* lstm_b_hh= (const float*)d_in[18];
  const int* srcp = ei;
  const int* dstp = ei + N_EDGES;

  char* ws = (char*)d_ws;
  size_t off = 0;
  auto alloc = [&](size_t bytes) { void* p = ws + off; off += (bytes + 255) & ~(size_t)255; return p; };
  float* h     = (float*)alloc((size_t)N_NODES * 64 * 4);
  float* agg   = (float*)alloc((size_t)N_NODES * 64 * 4);
  float* deg   = (float*)alloc((size_t)N_NODES * 4);
  float* ev    = (float*)alloc((size_t)N_NODES * 4);
  int*   startv= (int*)alloc(65 * 4);
  float* r1    = (float*)alloc((size_t)N_EDGES * HID * 4);      // 10.24 MB
  u16*   w2qT  = (u16*)alloc((size_t)KTOT * 64 * 2);            // 1.06 MB
  u16*   G     = (u16*)alloc((size_t)N_NODES * GSTRIDE * 2);    // 82.6 MB
  bool useG = (ws_size >= off);

  hipMemsetAsync(deg, 0, (size_t)N_NODES * 4, stream);

  k_lin0<<<(N_NODES + 3) / 4, 256, 0, stream>>>(x, lin0_w, lin0_b, h);
  k_deg<<<(N_EDGES + 255) / 256, 256, 0, stream>>>(dstp, deg);
  k_bounds<<<1, 128, 0, stream>>>(batch, startv);

  if (useG) {
    k_r1<<<N_EDGES, HID, 0, stream>>>(ea, nn_w1, nn_b1, r1);
    k_w2p<<<(KTOT * 64 + 255) / 256, 256, 0, stream>>>(nn_w2, nn_b2, w2qT);
    for (int it = 0; it < 3; ++it) {
      hipMemsetAsync(agg, 0, (size_t)N_NODES * 64 * 4, stream);
      k_Gm<<<dim3((N_NODES + 63) / 64, (KTOT + 255) / 256), 256, 0, stream>>>(h, w2qT, G);
      k_msg2<<<N_EDGES / 4, 256, 0, stream>>>(srcp, dstp, r1, G, agg);
      k_gru<<<N_NODES, 192, 0, stream>>>(agg, deg, conv_b, gru_w_ih, gru_w_hh,
                                         gru_b_ih, gru_b_hh, h);
    }
  } else {
    for (int it = 0; it < 3; ++it) {
      hipMemsetAsync(agg, 0, (size_t)N_NODES * 64 * 4, stream);
      k_msgv<<<dim3(313, KY_SPLIT), 256, 0, stream>>>(srcp, dstp, h, ea, nn_w1, nn_b1,
                                                      nn_w2, nn_b2, agg);
      k_gru<<<N_NODES, 192, 0, stream>>>(agg, deg, conv_b, gru_w_ih, gru_w_hh,
                                         gru_b_ih, gru_b_hh, h);
    }
  }

  k_s2s<<<B_GRAPHS, 256, 0, stream>>>(lstm_w_ih, lstm_w_hh, lstm_b_ih, lstm_b_hh,
                                      h, startv, ev, (float*)d_out);
  k_outf<<<(N_NODES * 64 + 255) / 256, 256, 0, stream>>>(h, (float*)d_out);
}

// Round 10
// 549.492 us; speedup vs baseline: 6.3047x; 1.0033x over previous
//
#include <hip/hip_runtime.h>

#define N_NODES 5000
#define N_EDGES 20000
#define B_GRAPHS 64
#define DD 64
#define HID 128
#define EDGE_FEAT 5
#define KTOT 8256   // 8192 + 64 bias cols
#define GSTRIDE 8256
#define KY_SPLIT 8
#define KCHUNK 1032
#define GNB 16      // nodes per k_gru2 block

typedef unsigned short u16;
typedef float f32x4 __attribute__((ext_vector_type(4)));
typedef u16 u16x8 __attribute__((ext_vector_type(8)));
typedef __bf16 bf16x8 __attribute__((ext_vector_type(8)));
union AB { u16x8 u; bf16x8 b; };

__device__ __forceinline__ float b2f(u16 u) {
  union { unsigned u32; float f; } v; v.u32 = ((unsigned)u) << 16; return v.f;
}
__device__ __forceinline__ u16 f2b(float f) {
  union { float f; unsigned u; } v; v.f = f;
  unsigned r = v.u + 0x7FFF + ((v.u >> 16) & 1);
  return (u16)(r >> 16);
}
__device__ __forceinline__ float sigf(float x) { return 1.f / (1.f + expf(-x)); }

// -------------------- lin0: h = relu(x @ W + b), 4 nodes/block --------------------
__global__ __launch_bounds__(256) void k_lin0(const float* __restrict__ x, const float* __restrict__ w,
                       const float* __restrict__ b, float* __restrict__ h) {
  __shared__ float xs[4][64];
  int wv = threadIdx.x >> 6, j = threadIdx.x & 63;
  int n = blockIdx.x * 4 + wv;
  if (n >= N_NODES) return;
  xs[wv][j] = x[(size_t)n * 64 + j];
  __syncthreads();
  float acc = b[j];
#pragma unroll
  for (int i = 0; i < 64; ++i) acc += xs[wv][i] * w[i * 64 + j];
  h[(size_t)n * 64 + j] = fmaxf(acc, 0.f);
}

// -------------------- deg (atomic count) --------------------
__global__ void k_deg(const int* __restrict__ dst, float* __restrict__ deg) {
  int e = blockIdx.x * 256 + threadIdx.x;
  if (e < N_EDGES) atomicAdd(&deg[dst[e]], 1.0f);
}

// -------------------- graph boundaries in sorted batch --------------------
__global__ void k_bounds(const int* __restrict__ batch, int* __restrict__ start) {
  int g = threadIdx.x;
  if (g > B_GRAPHS) return;
  int lo = 0, hi = N_NODES;
  while (lo < hi) { int mid = (lo + hi) >> 1; if (batch[mid] < g) lo = mid + 1; else hi = mid; }
  start[g] = lo;
}

// -------------------- r1 = relu(edge_attr @ W1 + b1) --------------------
__global__ void k_r1(const float* __restrict__ ea, const float* __restrict__ w1,
                     const float* __restrict__ b1, float* __restrict__ r1) {
  __shared__ float a[EDGE_FEAT];
  int e = blockIdx.x, t = threadIdx.x;
  if (t < EDGE_FEAT) a[t] = ea[e * EDGE_FEAT + t];
  __syncthreads();
  float acc = b1[t];
#pragma unroll
  for (int k = 0; k < EDGE_FEAT; ++k) acc += a[k] * w1[k * HID + t];
  r1[e * HID + t] = fmaxf(acc, 0.f);
}

// ---------- w2qT[c][i] = bf16(w2[c>>6][i*64 + (c&63)]), c<8192; else b2[i*64+(c-8192)] ----
__global__ void k_w2p(const float* __restrict__ w2, const float* __restrict__ b2,
                      u16* __restrict__ w2qT) {
  int idx = blockIdx.x * 256 + threadIdx.x;
  if (idx >= KTOT * 64) return;
  int c = idx >> 6, i = idx & 63;
  float v = (c < 8192) ? w2[(size_t)(c >> 6) * 4096 + i * 64 + (c & 63)]
                       : b2[i * 64 + (c - 8192)];
  w2qT[idx] = f2b(v);
}

// -------------------- G = h @ W2q via MFMA bf16; G stored bf16 --------------------
__global__ __launch_bounds__(256) void k_Gm(const float* __restrict__ h,
                                            const u16* __restrict__ w2qT,
                                            u16* __restrict__ G) {
  __shared__ u16 hsb[64][72];
  __shared__ u16 outs[64][264];
  int row0 = blockIdx.x * 64, c0 = blockIdx.y * 256;
  int t = threadIdx.x, w = t >> 6, lane = t & 63;

  {
    int r = t >> 2, qp = t & 3;
    int row = row0 + r;
#pragma unroll
    for (int i = 0; i < 16; ++i) {
      float v = (row < N_NODES) ? h[(size_t)row * 64 + qp * 16 + i] : 0.f;
      hsb[r][qp * 16 + i] = f2b(v);
    }
  }
  __syncthreads();

  f32x4 acc[4][4];
#pragma unroll
  for (int rt = 0; rt < 4; ++rt)
#pragma unroll
    for (int ct = 0; ct < 4; ++ct) acc[rt][ct] = (f32x4){0.f, 0.f, 0.f, 0.f};

  int colbase = c0 + w * 64;
#pragma unroll
  for (int ks = 0; ks < 2; ++ks) {
    int kb = ks * 32 + (lane >> 4) * 8;
    AB afr[4];
#pragma unroll
    for (int rt = 0; rt < 4; ++rt)
      afr[rt].u = *(const u16x8*)&hsb[rt * 16 + (lane & 15)][kb];
#pragma unroll
    for (int ct = 0; ct < 4; ++ct) {
      int c = colbase + ct * 16 + (lane & 15);
      AB bfr;
      if (c < KTOT) bfr.u = *(const u16x8*)(w2qT + (size_t)c * 64 + kb);
      else bfr.u = (u16x8){0, 0, 0, 0, 0, 0, 0, 0};
#pragma unroll
      for (int rt = 0; rt < 4; ++rt)
        acc[rt][ct] = __builtin_amdgcn_mfma_f32_16x16x32_bf16(afr[rt].b, bfr.b, acc[rt][ct], 0, 0, 0);
    }
  }

#pragma unroll
  for (int rt = 0; rt < 4; ++rt)
#pragma unroll
    for (int ct = 0; ct < 4; ++ct) {
      int lcol = w * 64 + ct * 16 + (lane & 15);
      int lrow0 = rt * 16 + (lane >> 4) * 4;
#pragma unroll
      for (int r = 0; r < 4; ++r) outs[lrow0 + r][lcol] = f2b(acc[rt][ct][r]);
    }
  __syncthreads();

  {
    int r = t >> 2, seg = t & 3;
    int row = row0 + r;
    if (row < N_NODES) {
#pragma unroll
      for (int i = 0; i < 8; ++i) {
        int c = seg * 64 + i * 8;
        int gc = c0 + c;
        if (gc < KTOT)
          *(u16x8*)(G + (size_t)row * GSTRIDE + gc) = *(const u16x8*)&outs[r][c];
      }
    }
  }
}

// -------------------- msg2: agg[dst] += r1[e] @ G[src] (+bias col), vectorized ----------
// 32 edges/block; wave handles 8 edges; lane = (edge l>>3, colgroup (l&7)*8); u16x8 loads.
__global__ __launch_bounds__(256) void k_msg2(const int* __restrict__ src,
                                              const int* __restrict__ dst,
                                              const float* __restrict__ r1,
                                              const u16* __restrict__ G,
                                              float* __restrict__ agg) {
  __shared__ float r1s[32][128];
  __shared__ int ss[32], ds[32];
  int t = threadIdx.x;
  int e0 = blockIdx.x * 32;   // N_EDGES % 32 == 0
  for (int idx = t; idx < 32 * 128; idx += 256) {
    int e = idx >> 7, k = idx & 127;
    r1s[e][k] = r1[(size_t)(e0 + e) * HID + k];
  }
  if (t < 32) { ss[t] = src[e0 + t]; ds[t] = dst[e0 + t]; }
  __syncthreads();

  int w = t >> 6, l = t & 63;
  int le = w * 8 + (l >> 3);
  int c0 = (l & 7) * 8;
  const u16* Gs = G + (size_t)ss[le] * GSTRIDE;

  float acc[8];
  {
    u16x8 bv = *(const u16x8*)(Gs + 8192 + c0);
#pragma unroll
    for (int j = 0; j < 8; ++j) acc[j] = b2f(bv[j]);
  }
#pragma unroll 8
  for (int kap = 0; kap < 128; ++kap) {
    u16x8 gv = *(const u16x8*)(Gs + kap * 64 + c0);
    float rv = r1s[le][kap];
#pragma unroll
    for (int j = 0; j < 8; ++j) acc[j] += rv * b2f(gv[j]);
  }

  float* ap = agg + (size_t)ds[le] * 64 + c0;
#pragma unroll
  for (int j = 0; j < 8; ++j) atomicAdd(&ap[j], acc[j]);
}

// -------------------- fallback: fused msg (VALU; r1 recomputed in-block) ----------
__global__ __launch_bounds__(256) void k_msgv(const int* __restrict__ src,
                                              const int* __restrict__ dst,
                                              const float* __restrict__ h,
                                              const float* __restrict__ ea,
                                              const float* __restrict__ w1,
                                              const float* __restrict__ b1,
                                              const float* __restrict__ w2,
                                              const float* __restrict__ b2,
                                              float* __restrict__ agg) {
  __shared__ float hs[64][68];
  __shared__ float r1sv[64][132];
  __shared__ float w1s[EDGE_FEAT][HID];
  __shared__ float b1s[HID];
  __shared__ float eas[64][EDGE_FEAT];
  __shared__ int dsts[64];

  int bm = blockIdx.x, ky = blockIdx.y;
  int t = threadIdx.x;
  int wave = t >> 6, lane = t & 63;

  if (t < HID) b1s[t] = b1[t];
  for (int i = t; i < EDGE_FEAT * HID; i += 256) w1s[i / HID][i % HID] = w1[i];
  {
    int r = t >> 2, qp = t & 3;
    int e = bm * 64 + r;
    if (t < 64) dsts[t] = (bm * 64 + t < N_EDGES) ? dst[bm * 64 + t] : -1;
    if (e < N_EDGES) {
      int s = src[e];
#pragma unroll
      for (int i = 0; i < 16; ++i) hs[r][qp * 16 + i] = h[(size_t)s * 64 + qp * 16 + i];
      if (qp == 0)
#pragma unroll
        for (int k = 0; k < EDGE_FEAT; ++k) eas[r][k] = ea[(size_t)e * EDGE_FEAT + k];
    } else {
#pragma unroll
      for (int i = 0; i < 16; ++i) hs[r][qp * 16 + i] = 0.f;
      if (qp == 0)
#pragma unroll
        for (int k = 0; k < EDGE_FEAT; ++k) eas[r][k] = 0.f;
    }
  }
  __syncthreads();

  for (int idx = t; idx < 64 * HID; idx += 256) {
    int rr = idx >> 7, c = idx & 127;
    float acc = b1s[c];
#pragma unroll
    for (int k = 0; k < EDGE_FEAT; ++k) acc += eas[rr][k] * w1s[k][c];
    r1sv[rr][c] = fmaxf(acc, 0.f);
  }
  if (t < 64) r1sv[t][128] = 1.0f;
  __syncthreads();

  int row0 = wave * 16 + (lane >> 4) * 4;
  int colb = lane & 15;

  float acc[4][4];
#pragma unroll
  for (int ct = 0; ct < 4; ++ct)
#pragma unroll
    for (int r = 0; r < 4; ++r) acc[ct][r] = 0.f;

  int k0 = ky * KCHUNK, k1 = k0 + KCHUNK;
  for (int kp = k0; kp < k1; ++kp) {
    int kap = kp >> 6, ii = kp & 63;
    const float* Bp = (kp < 8192) ? (w2 + (size_t)kp * 64)
                                  : (b2 + (size_t)(kp - 8192) * 64);
    float bv[4];
#pragma unroll
    for (int ct = 0; ct < 4; ++ct) bv[ct] = Bp[ct * 16 + colb];
#pragma unroll
    for (int r = 0; r < 4; ++r) {
      float a = r1sv[row0 + r][kap] * hs[row0 + r][ii];
#pragma unroll
      for (int ct = 0; ct < 4; ++ct) acc[ct][r] += a * bv[ct];
    }
  }

#pragma unroll
  for (int ct = 0; ct < 4; ++ct) {
    int col = ct * 16 + colb;
#pragma unroll
    for (int r = 0; r < 4; ++r) {
      int dd = dsts[row0 + r];
      if (dd >= 0) atomicAdd(&agg[(size_t)dd * 64 + col], acc[ct][r]);
    }
  }
}

// -------------------- GRU step, 16 nodes/block, weights in VGPRs ----------
__global__ __launch_bounds__(256) void k_gru2(const float* __restrict__ agg, const float* __restrict__ deg,
                                              const float* __restrict__ conv_b,
                                              const float* __restrict__ wih, const float* __restrict__ whh,
                                              const float* __restrict__ bih, const float* __restrict__ bhh,
                                              float* __restrict__ h) {
  __shared__ float ms[GNB][64], hsn[GNB][64];
  __shared__ float gis[GNB][192], ghs[GNB][192];
  int n0 = blockIdx.x * GNB;
  int t = threadIdx.x;

  for (int idx = t; idx < GNB * 64; idx += 256) {
    int r = idx >> 6, c = idx & 63;
    int n = n0 + r;
    if (n < N_NODES) {
      float dg = fmaxf(deg[n], 1.0f);
      ms[r][c] = fmaxf(agg[(size_t)n * 64 + c] / dg + conv_b[c], 0.f);
      hsn[r][c] = h[(size_t)n * 64 + c];
    } else { ms[r][c] = 0.f; hsn[r][c] = 0.f; }
  }
  __syncthreads();

  if (t < 192) {
    f32x4 wr[16];
    const f32x4* wp = (const f32x4*)(wih + (size_t)t * 64);
#pragma unroll
    for (int i = 0; i < 16; ++i) wr[i] = wp[i];
    float bi = bih[t];
    for (int n = 0; n < GNB; ++n) {
      float acc = bi;
#pragma unroll
      for (int i = 0; i < 16; ++i) {
        f32x4 v = wr[i];
        acc += ms[n][4*i] * v.x + ms[n][4*i+1] * v.y + ms[n][4*i+2] * v.z + ms[n][4*i+3] * v.w;
      }
      gis[n][t] = acc;
    }
    const f32x4* hp = (const f32x4*)(whh + (size_t)t * 64);
#pragma unroll
    for (int i = 0; i < 16; ++i) wr[i] = hp[i];
    float bh = bhh[t];
    for (int n = 0; n < GNB; ++n) {
      float acc = bh;
#pragma unroll
      for (int i = 0; i < 16; ++i) {
        f32x4 v = wr[i];
        acc += hsn[n][4*i] * v.x + hsn[n][4*i+1] * v.y + hsn[n][4*i+2] * v.z + hsn[n][4*i+3] * v.w;
      }
      ghs[n][t] = acc;
    }
  }
  __syncthreads();

  for (int idx = t; idx < GNB * 64; idx += 256) {
    int rr = idx >> 6, c = idx & 63;
    int n = n0 + rr;
    if (n < N_NODES) {
      float r = sigf(gis[rr][c] + ghs[rr][c]);
      float z = sigf(gis[rr][64 + c] + ghs[rr][64 + c]);
      float nn = tanhf(gis[rr][128 + c] + r * ghs[rr][128 + c]);
      h[(size_t)n * 64 + c] = (1.f - z) * nn + z * hsn[rr][c];
    }
  }
}

// -------------------- fused Set2Set: 1 block per graph, 3 steps in-kernel ----------
__global__ __launch_bounds__(256) void k_s2s(const float* __restrict__ wih, const float* __restrict__ whh,
                                             const float* __restrict__ bih, const float* __restrict__ bhh,
                                             const float* __restrict__ feat, const int* __restrict__ start,
                                             float* __restrict__ ev, float* __restrict__ outq) {
  __shared__ float qs[128], hhs[64], ccs[64], gates[256], part[4][64], redm[4];
  int g = blockIdx.x, t = threadIdx.x, w = t >> 6, l = t & 63;
  int s0 = start[g], s1 = start[g + 1];
  if (t < 128) qs[t] = 0.f;
  if (t < 64) { hhs[t] = 0.f; ccs[t] = 0.f; }
  __syncthreads();

  for (int step = 0; step < 3; ++step) {
    {
      float acc = bih[t] + bhh[t];
      const f32x4* wr = (const f32x4*)(wih + (size_t)t * 128);
#pragma unroll
      for (int i = 0; i < 32; ++i) {
        f32x4 v = wr[i];
        acc += qs[4 * i] * v.x + qs[4 * i + 1] * v.y + qs[4 * i + 2] * v.z + qs[4 * i + 3] * v.w;
      }
      const f32x4* hr = (const f32x4*)(whh + (size_t)t * 64);
#pragma unroll
      for (int i = 0; i < 16; ++i) {
        f32x4 v = hr[i];
        acc += hhs[4 * i] * v.x + hhs[4 * i + 1] * v.y + hhs[4 * i + 2] * v.z + hhs[4 * i + 3] * v.w;
      }
      gates[t] = acc;
    }
    __syncthreads();
    if (t < 64) {
      float c_new = sigf(gates[64 + t]) * ccs[t] + sigf(gates[t]) * tanhf(gates[128 + t]);
      hhs[t] = sigf(gates[192 + t]) * tanhf(c_new);
      ccs[t] = c_new;
      qs[t] = hhs[t];
    }
    __syncthreads();

    float mw = -1e30f;
    for (int n = s0 + w; n < s1; n += 4) {
      float v = feat[(size_t)n * 64 + l] * hhs[l];
#pragma unroll
      for (int off = 32; off; off >>= 1) v += __shfl_xor(v, off, 64);
      if (l == 0) ev[n] = v;
      mw = fmaxf(mw, v);
    }
    if (l == 0) redm[w] = mw;
    __syncthreads();
    float emax = fmaxf(fmaxf(redm[0], redm[1]), fmaxf(redm[2], redm[3]));
    float sd = 0.f;
    for (int n = s0 + t; n < s1; n += 256) sd += expf(ev[n] - emax);
    gates[t] = sd; __syncthreads();
    for (int off = 128; off; off >>= 1) { if (t < off) gates[t] += gates[t + off]; __syncthreads(); }
    float den = gates[0];
    __syncthreads();
    float pacc = 0.f;
    for (int n = s0 + w; n < s1; n += 4) {
      float a = expf(ev[n] - emax) / den;
      pacc += a * feat[(size_t)n * 64 + l];
    }
    part[w][l] = pacc; __syncthreads();
    if (t < 64) qs[64 + t] = part[0][t] + part[1][t] + part[2][t] + part[3][t];
    __syncthreads();
  }
  if (t < 128) outq[g * 128 + t] = qs[t];
}

// -------------------- feat part of output --------------------
__global__ void k_outf(const float* __restrict__ h, float* __restrict__ out) {
  int i = blockIdx.x * 256 + threadIdx.x;
  if (i < N_NODES * 64) out[B_GRAPHS * 128 + i] = h[i];
}

extern "C" void kernel_launch(void* const* d_in, const int* in_sizes, int n_in,
                              void* d_out, int out_size, void* d_ws, size_t ws_size,
                              hipStream_t stream) {
  (void)in_sizes; (void)n_in; (void)out_size;
  const float* x        = (const float*)d_in[0];
  const int*   ei       = (const int*)d_in[1];
  const int*   batch    = (const int*)d_in[2];
  const float* ea       = (const float*)d_in[3];
  const float* lin0_w   = (const float*)d_in[4];
  const float* lin0_b   = (const float*)d_in[5];
  const float* nn_w1    = (const float*)d_in[6];
  const float* nn_b1    = (const float*)d_in[7];
  const float* nn_w2    = (const float*)d_in[8];
  const float* nn_b2    = (const float*)d_in[9];
  const float* conv_b   = (const float*)d_in[10];
  const float* gru_w_ih = (const float*)d_in[11];
  const float* gru_w_hh = (const float*)d_in[12];
  const float* gru_b_ih = (const float*)d_in[13];
  const float* gru_b_hh = (const float*)d_in[14];
  const float* lstm_w_ih= (const float*)d_in[15];
  const float* lstm_w_hh= (const float*)d_in[16];
  const float* lstm_b_ih= (const float*)d_in[17];
  const float* lstm_b_hh= (const float*)d_in[18];
  const int* srcp = ei;
  const int* dstp = ei + N_EDGES;

  char* ws = (char*)d_ws;
  size_t off = 0;
  auto alloc = [&](size_t bytes) { void* p = ws + off; off += (bytes + 255) & ~(size_t)255; return p; };
  float* h     = (float*)alloc((size_t)N_NODES * 64 * 4);
  float* agg   = (float*)alloc((size_t)N_NODES * 64 * 4);
  float* deg   = (float*)alloc((size_t)N_NODES * 4);
  float* ev    = (float*)alloc((size_t)N_NODES * 4);
  int*   startv= (int*)alloc(65 * 4);
  float* r1    = (float*)alloc((size_t)N_EDGES * HID * 4);
  u16*   w2qT  = (u16*)alloc((size_t)KTOT * 64 * 2);
  u16*   G     = (u16*)alloc((size_t)N_NODES * GSTRIDE * 2);
  bool useG = (ws_size >= off);

  hipMemsetAsync(deg, 0, (size_t)N_NODES * 4, stream);

  k_lin0<<<(N_NODES + 3) / 4, 256, 0, stream>>>(x, lin0_w, lin0_b, h);
  k_deg<<<(N_EDGES + 255) / 256, 256, 0, stream>>>(dstp, deg);
  k_bounds<<<1, 128, 0, stream>>>(batch, startv);

  if (useG) {
    k_r1<<<N_EDGES, HID, 0, stream>>>(ea, nn_w1, nn_b1, r1);
    k_w2p<<<(KTOT * 64 + 255) / 256, 256, 0, stream>>>(nn_w2, nn_b2, w2qT);
    for (int it = 0; it < 3; ++it) {
      hipMemsetAsync(agg, 0, (size_t)N_NODES * 64 * 4, stream);
      k_Gm<<<dim3((N_NODES + 63) / 64, (KTOT + 255) / 256), 256, 0, stream>>>(h, w2qT, G);
      k_msg2<<<N_EDGES / 32, 256, 0, stream>>>(srcp, dstp, r1, G, agg);
      k_gru2<<<(N_NODES + GNB - 1) / GNB, 256, 0, stream>>>(agg, deg, conv_b, gru_w_ih, gru_w_hh,
                                                            gru_b_ih, gru_b_hh, h);
    }
  } else {
    for (int it = 0; it < 3; ++it) {
      hipMemsetAsync(agg, 0, (size_t)N_NODES * 64 * 4, stream);
      k_msgv<<<dim3(313, KY_SPLIT), 256, 0, stream>>>(srcp, dstp, h, ea, nn_w1, nn_b1,
                                                      nn_w2, nn_b2, agg);
      k_gru2<<<(N_NODES + GNB - 1) / GNB, 256, 0, stream>>>(agg, deg, conv_b, gru_w_ih, gru_w_hh,
                                                            gru_b_ih, gru_b_hh, h);
    }
  }

  k_s2s<<<B_GRAPHS, 256, 0, stream>>>(lstm_w_ih, lstm_w_hh, lstm_b_ih, lstm_b_hh,
                                      h, startv, ev, (float*)d_out);
  k_outf<<<(N_NODES * 64 + 255) / 256, 256, 0, stream>>>(h, (float*)d_out);
}

// Round 11
// 441.850 us; speedup vs baseline: 7.8406x; 1.2436x over previous
//
#include <hip/hip_runtime.h>

#define N_NODES 5000
#define N_EDGES 20000
#define B_GRAPHS 64
#define DD 64
#define HID 128
#define EDGE_FEAT 5
#define KTOT 8256   // 8192 + 64 bias cols
#define GSTRIDE 8256
#define KY_SPLIT 8
#define KCHUNK 1032
#define GNB 16      // nodes per k_gru2 block

typedef unsigned short u16;
typedef float f32x4 __attribute__((ext_vector_type(4)));
typedef u16 u16x8 __attribute__((ext_vector_type(8)));
typedef __bf16 bf16x8 __attribute__((ext_vector_type(8)));
union AB { u16x8 u; bf16x8 b; };

__device__ __forceinline__ float b2f(u16 u) {
  union { unsigned u32; float f; } v; v.u32 = ((unsigned)u) << 16; return v.f;
}
__device__ __forceinline__ u16 f2b(float f) {
  union { float f; unsigned u; } v; v.f = f;
  unsigned r = v.u + 0x7FFF + ((v.u >> 16) & 1);
  return (u16)(r >> 16);
}
__device__ __forceinline__ float sigf(float x) { return 1.f / (1.f + expf(-x)); }

// -------------------- lin0: h = relu(x @ W + b), 4 nodes/block --------------------
__global__ __launch_bounds__(256) void k_lin0(const float* __restrict__ x, const float* __restrict__ w,
                       const float* __restrict__ b, float* __restrict__ h) {
  __shared__ float xs[4][64];
  int wv = threadIdx.x >> 6, j = threadIdx.x & 63;
  int n = blockIdx.x * 4 + wv;
  if (n >= N_NODES) return;
  xs[wv][j] = x[(size_t)n * 64 + j];
  __syncthreads();
  float acc = b[j];
#pragma unroll
  for (int i = 0; i < 64; ++i) acc += xs[wv][i] * w[i * 64 + j];
  h[(size_t)n * 64 + j] = fmaxf(acc, 0.f);
}

// -------------------- deg (atomic count, dst side) --------------------
__global__ void k_deg(const int* __restrict__ dst, float* __restrict__ deg) {
  int e = blockIdx.x * 256 + threadIdx.x;
  if (e < N_EDGES) atomicAdd(&deg[dst[e]], 1.0f);
}

// -------------------- CSR by src: count --------------------
__global__ void k_cnt(const int* __restrict__ src, int* __restrict__ cnt) {
  int e = blockIdx.x * 256 + threadIdx.x;
  if (e < N_EDGES) atomicAdd(&cnt[src[e]], 1);
}

// -------------------- CSR: block-wide exclusive scan over 5000 --------------------
__global__ void k_scan(const int* __restrict__ cnt, int* __restrict__ starts,
                       int* __restrict__ ptr2) {
  __shared__ int buf[256];
  __shared__ int carry;
  int t = threadIdx.x;
  if (t == 0) carry = 0;
  __syncthreads();
  for (int base = 0; base < N_NODES; base += 256) {
    int v = (base + t < N_NODES) ? cnt[base + t] : 0;
    buf[t] = v;
    __syncthreads();
    for (int off = 1; off < 256; off <<= 1) {
      int add = (t >= off) ? buf[t - off] : 0;
      __syncthreads();
      buf[t] += add;
      __syncthreads();
    }
    if (base + t < N_NODES) {
      int excl = carry + buf[t] - v;
      starts[base + t] = excl;
      ptr2[base + t] = excl;
    }
    __syncthreads();
    if (t == 0) carry += buf[255];
    __syncthreads();
  }
  if (t == 0) starts[N_NODES] = carry;
}

// -------------------- CSR: place edge ids --------------------
__global__ void k_place(const int* __restrict__ src, int* __restrict__ ptr2,
                        int* __restrict__ eidx) {
  int e = blockIdx.x * 256 + threadIdx.x;
  if (e < N_EDGES) {
    int pos = atomicAdd(&ptr2[src[e]], 1);
    eidx[pos] = e;
  }
}

// -------------------- graph boundaries in sorted batch --------------------
__global__ void k_bounds(const int* __restrict__ batch, int* __restrict__ start) {
  int g = threadIdx.x;
  if (g > B_GRAPHS) return;
  int lo = 0, hi = N_NODES;
  while (lo < hi) { int mid = (lo + hi) >> 1; if (batch[mid] < g) lo = mid + 1; else hi = mid; }
  start[g] = lo;
}

// -------------------- r1 = relu(edge_attr @ W1 + b1) --------------------
__global__ void k_r1(const float* __restrict__ ea, const float* __restrict__ w1,
                     const float* __restrict__ b1, float* __restrict__ r1) {
  __shared__ float a[EDGE_FEAT];
  int e = blockIdx.x, t = threadIdx.x;
  if (t < EDGE_FEAT) a[t] = ea[e * EDGE_FEAT + t];
  __syncthreads();
  float acc = b1[t];
#pragma unroll
  for (int k = 0; k < EDGE_FEAT; ++k) acc += a[k] * w1[k * HID + t];
  r1[e * HID + t] = fmaxf(acc, 0.f);
}

// ---------- w2qT[c][i] = bf16(w2[c>>6][i*64 + (c&63)]), c<8192; else b2[i*64+(c-8192)] ----
__global__ void k_w2p(const float* __restrict__ w2, const float* __restrict__ b2,
                      u16* __restrict__ w2qT) {
  int idx = blockIdx.x * 256 + threadIdx.x;
  if (idx >= KTOT * 64) return;
  int c = idx >> 6, i = idx & 63;
  float v = (c < 8192) ? w2[(size_t)(c >> 6) * 4096 + i * 64 + (c & 63)]
                       : b2[i * 64 + (c - 8192)];
  w2qT[idx] = f2b(v);
}

// -------------------- G = h @ W2q via MFMA bf16; G stored bf16 --------------------
__global__ __launch_bounds__(256) void k_Gm(const float* __restrict__ h,
                                            const u16* __restrict__ w2qT,
                                            u16* __restrict__ G) {
  __shared__ u16 hsb[64][72];
  __shared__ u16 outs[64][264];
  int row0 = blockIdx.x * 64, c0 = blockIdx.y * 256;
  int t = threadIdx.x, w = t >> 6, lane = t & 63;

  {
    int r = t >> 2, qp = t & 3;
    int row = row0 + r;
#pragma unroll
    for (int i = 0; i < 16; ++i) {
      float v = (row < N_NODES) ? h[(size_t)row * 64 + qp * 16 + i] : 0.f;
      hsb[r][qp * 16 + i] = f2b(v);
    }
  }
  __syncthreads();

  f32x4 acc[4][4];
#pragma unroll
  for (int rt = 0; rt < 4; ++rt)
#pragma unroll
    for (int ct = 0; ct < 4; ++ct) acc[rt][ct] = (f32x4){0.f, 0.f, 0.f, 0.f};

  int colbase = c0 + w * 64;
#pragma unroll
  for (int ks = 0; ks < 2; ++ks) {
    int kb = ks * 32 + (lane >> 4) * 8;
    AB afr[4];
#pragma unroll
    for (int rt = 0; rt < 4; ++rt)
      afr[rt].u = *(const u16x8*)&hsb[rt * 16 + (lane & 15)][kb];
#pragma unroll
    for (int ct = 0; ct < 4; ++ct) {
      int c = colbase + ct * 16 + (lane & 15);
      AB bfr;
      if (c < KTOT) bfr.u = *(const u16x8*)(w2qT + (size_t)c * 64 + kb);
      else bfr.u = (u16x8){0, 0, 0, 0, 0, 0, 0, 0};
#pragma unroll
      for (int rt = 0; rt < 4; ++rt)
        acc[rt][ct] = __builtin_amdgcn_mfma_f32_16x16x32_bf16(afr[rt].b, bfr.b, acc[rt][ct], 0, 0, 0);
    }
  }

#pragma unroll
  for (int rt = 0; rt < 4; ++rt)
#pragma unroll
    for (int ct = 0; ct < 4; ++ct) {
      int lcol = w * 64 + ct * 16 + (lane & 15);
      int lrow0 = rt * 16 + (lane >> 4) * 4;
#pragma unroll
      for (int r = 0; r < 4; ++r) outs[lrow0 + r][lcol] = f2b(acc[rt][ct][r]);
    }
  __syncthreads();

  {
    int r = t >> 2, seg = t & 3;
    int row = row0 + r;
    if (row < N_NODES) {
#pragma unroll
      for (int i = 0; i < 8; ++i) {
        int c = seg * 64 + i * 8;
        int gc = c0 + c;
        if (gc < KTOT)
          *(u16x8*)(G + (size_t)row * GSTRIDE + gc) = *(const u16x8*)&outs[r][c];
      }
    }
  }
}

// -------------------- msg3: CSR-by-src, G row staged in LDS --------------------
// Block per source node: load G[s] (16.5 KB) once; per outgoing edge, 4-wave
// split-kappa dot + cross-wave reduce + one atomicAdd per (dst,col).
__global__ __launch_bounds__(256) void k_msg3(const int* __restrict__ starts,
                                              const int* __restrict__ eidx,
                                              const int* __restrict__ dst,
                                              const float* __restrict__ r1,
                                              const u16* __restrict__ G,
                                              float* __restrict__ agg) {
  __shared__ u16 grow[128 * 64];
  __shared__ float gbias[64];
  __shared__ float r1e[128];
  __shared__ float part[4][64];
  int s = blockIdx.x;
  int e0 = starts[s], e1 = starts[s + 1];
  if (e0 >= e1) return;
  int t = threadIdx.x, w = t >> 6, l = t & 63;

  const u16* Gs = G + (size_t)s * GSTRIDE;
#pragma unroll
  for (int i = 0; i < 4; ++i)
    *(u16x8*)(grow + t * 8 + i * 2048) = *(const u16x8*)(Gs + t * 8 + i * 2048);
  if (t < 64) gbias[t] = b2f(Gs[8192 + t]);
  __syncthreads();

  for (int ei = e0; ei < e1; ++ei) {
    int e = eidx[ei];
    if (t < 128) r1e[t] = r1[(size_t)e * HID + t];
    __syncthreads();
    float acc = 0.f;
    const u16* gw = grow + w * 32 * 64 + l;
#pragma unroll 8
    for (int kap = 0; kap < 32; ++kap)
      acc += r1e[w * 32 + kap] * b2f(gw[kap * 64]);
    part[w][l] = acc;
    __syncthreads();
    if (t < 64) {
      float v = part[0][l] + part[1][l] + part[2][l] + part[3][l] + gbias[l];
      atomicAdd(&agg[(size_t)dst[e] * 64 + l], v);
    }
    __syncthreads();
  }
}

// -------------------- fallback: fused msg (VALU; r1 recomputed in-block) ----------
__global__ __launch_bounds__(256) void k_msgv(const int* __restrict__ src,
                                              const int* __restrict__ dst,
                                              const float* __restrict__ h,
                                              const float* __restrict__ ea,
                                              const float* __restrict__ w1,
                                              const float* __restrict__ b1,
                                              const float* __restrict__ w2,
                                              const float* __restrict__ b2,
                                              float* __restrict__ agg) {
  __shared__ float hs[64][68];
  __shared__ float r1sv[64][132];
  __shared__ float w1s[EDGE_FEAT][HID];
  __shared__ float b1s[HID];
  __shared__ float eas[64][EDGE_FEAT];
  __shared__ int dsts[64];

  int bm = blockIdx.x, ky = blockIdx.y;
  int t = threadIdx.x;
  int wave = t >> 6, lane = t & 63;

  if (t < HID) b1s[t] = b1[t];
  for (int i = t; i < EDGE_FEAT * HID; i += 256) w1s[i / HID][i % HID] = w1[i];
  {
    int r = t >> 2, qp = t & 3;
    int e = bm * 64 + r;
    if (t < 64) dsts[t] = (bm * 64 + t < N_EDGES) ? dst[bm * 64 + t] : -1;
    if (e < N_EDGES) {
      int s = src[e];
#pragma unroll
      for (int i = 0; i < 16; ++i) hs[r][qp * 16 + i] = h[(size_t)s * 64 + qp * 16 + i];
      if (qp == 0)
#pragma unroll
        for (int k = 0; k < EDGE_FEAT; ++k) eas[r][k] = ea[(size_t)e * EDGE_FEAT + k];
    } else {
#pragma unroll
      for (int i = 0; i < 16; ++i) hs[r][qp * 16 + i] = 0.f;
      if (qp == 0)
#pragma unroll
        for (int k = 0; k < EDGE_FEAT; ++k) eas[r][k] = 0.f;
    }
  }
  __syncthreads();

  for (int idx = t; idx < 64 * HID; idx += 256) {
    int rr = idx >> 7, c = idx & 127;
    float acc = b1s[c];
#pragma unroll
    for (int k = 0; k < EDGE_FEAT; ++k) acc += eas[rr][k] * w1s[k][c];
    r1sv[rr][c] = fmaxf(acc, 0.f);
  }
  if (t < 64) r1sv[t][128] = 1.0f;
  __syncthreads();

  int row0 = wave * 16 + (lane >> 4) * 4;
  int colb = lane & 15;

  float acc[4][4];
#pragma unroll
  for (int ct = 0; ct < 4; ++ct)
#pragma unroll
    for (int r = 0; r < 4; ++r) acc[ct][r] = 0.f;

  int k0 = ky * KCHUNK, k1 = k0 + KCHUNK;
  for (int kp = k0; kp < k1; ++kp) {
    int kap = kp >> 6, ii = kp & 63;
    const float* Bp = (kp < 8192) ? (w2 + (size_t)kp * 64)
                                  : (b2 + (size_t)(kp - 8192) * 64);
    float bv[4];
#pragma unroll
    for (int ct = 0; ct < 4; ++ct) bv[ct] = Bp[ct * 16 + colb];
#pragma unroll
    for (int r = 0; r < 4; ++r) {
      float a = r1sv[row0 + r][kap] * hs[row0 + r][ii];
#pragma unroll
      for (int ct = 0; ct < 4; ++ct) acc[ct][r] += a * bv[ct];
    }
  }

#pragma unroll
  for (int ct = 0; ct < 4; ++ct) {
    int col = ct * 16 + colb;
#pragma unroll
    for (int r = 0; r < 4; ++r) {
      int dd = dsts[row0 + r];
      if (dd >= 0) atomicAdd(&agg[(size_t)dd * 64 + col], acc[ct][r]);
    }
  }
}

// -------------------- GRU step, 16 nodes/block, weights in VGPRs ----------
__global__ __launch_bounds__(256) void k_gru2(const float* __restrict__ agg, const float* __restrict__ deg,
                                              const float* __restrict__ conv_b,
                                              const float* __restrict__ wih, const float* __restrict__ whh,
                                              const float* __restrict__ bih, const float* __restrict__ bhh,
                                              float* __restrict__ h) {
  __shared__ float ms[GNB][64], hsn[GNB][64];
  __shared__ float gis[GNB][192], ghs[GNB][192];
  int n0 = blockIdx.x * GNB;
  int t = threadIdx.x;

  for (int idx = t; idx < GNB * 64; idx += 256) {
    int r = idx >> 6, c = idx & 63;
    int n = n0 + r;
    if (n < N_NODES) {
      float dg = fmaxf(deg[n], 1.0f);
      ms[r][c] = fmaxf(agg[(size_t)n * 64 + c] / dg + conv_b[c], 0.f);
      hsn[r][c] = h[(size_t)n * 64 + c];
    } else { ms[r][c] = 0.f; hsn[r][c] = 0.f; }
  }
  __syncthreads();

  if (t < 192) {
    f32x4 wr[16];
    const f32x4* wp = (const f32x4*)(wih + (size_t)t * 64);
#pragma unroll
    for (int i = 0; i < 16; ++i) wr[i] = wp[i];
    float bi = bih[t];
    for (int n = 0; n < GNB; ++n) {
      float acc = bi;
#pragma unroll
      for (int i = 0; i < 16; ++i) {
        f32x4 v = wr[i];
        acc += ms[n][4*i] * v.x + ms[n][4*i+1] * v.y + ms[n][4*i+2] * v.z + ms[n][4*i+3] * v.w;
      }
      gis[n][t] = acc;
    }
    const f32x4* hp = (const f32x4*)(whh + (size_t)t * 64);
#pragma unroll
    for (int i = 0; i < 16; ++i) wr[i] = hp[i];
    float bh = bhh[t];
    for (int n = 0; n < GNB; ++n) {
      float acc = bh;
#pragma unroll
      for (int i = 0; i < 16; ++i) {
        f32x4 v = wr[i];
        acc += hsn[n][4*i] * v.x + hsn[n][4*i+1] * v.y + hsn[n][4*i+2] * v.z + hsn[n][4*i+3] * v.w;
      }
      ghs[n][t] = acc;
    }
  }
  __syncthreads();

  for (int idx = t; idx < GNB * 64; idx += 256) {
    int rr = idx >> 6, c = idx & 63;
    int n = n0 + rr;
    if (n < N_NODES) {
      float r = sigf(gis[rr][c] + ghs[rr][c]);
      float z = sigf(gis[rr][64 + c] + ghs[rr][64 + c]);
      float nn = tanhf(gis[rr][128 + c] + r * ghs[rr][128 + c]);
      h[(size_t)n * 64 + c] = (1.f - z) * nn + z * hsn[rr][c];
    }
  }
}

// -------------------- fused Set2Set: 1 block per graph, 3 steps in-kernel ----------
__global__ __launch_bounds__(256) void k_s2s(const float* __restrict__ wih, const float* __restrict__ whh,
                                             const float* __restrict__ bih, const float* __restrict__ bhh,
                                             const float* __restrict__ feat, const int* __restrict__ start,
                                             float* __restrict__ ev, float* __restrict__ outq) {
  __shared__ float qs[128], hhs[64], ccs[64], gates[256], part[4][64], redm[4];
  int g = blockIdx.x, t = threadIdx.x, w = t >> 6, l = t & 63;
  int s0 = start[g], s1 = start[g + 1];
  if (t < 128) qs[t] = 0.f;
  if (t < 64) { hhs[t] = 0.f; ccs[t] = 0.f; }
  __syncthreads();

  for (int step = 0; step < 3; ++step) {
    {
      float acc = bih[t] + bhh[t];
      const f32x4* wr = (const f32x4*)(wih + (size_t)t * 128);
#pragma unroll
      for (int i = 0; i < 32; ++i) {
        f32x4 v = wr[i];
        acc += qs[4 * i] * v.x + qs[4 * i + 1] * v.y + qs[4 * i + 2] * v.z + qs[4 * i + 3] * v.w;
      }
      const f32x4* hr = (const f32x4*)(whh + (size_t)t * 64);
#pragma unroll
      for (int i = 0; i < 16; ++i) {
        f32x4 v = hr[i];
        acc += hhs[4 * i] * v.x + hhs[4 * i + 1] * v.y + hhs[4 * i + 2] * v.z + hhs[4 * i + 3] * v.w;
      }
      gates[t] = acc;
    }
    __syncthreads();
    if (t < 64) {
      float c_new = sigf(gates[64 + t]) * ccs[t] + sigf(gates[t]) * tanhf(gates[128 + t]);
      hhs[t] = sigf(gates[192 + t]) * tanhf(c_new);
      ccs[t] = c_new;
      qs[t] = hhs[t];
    }
    __syncthreads();

    float mw = -1e30f;
    for (int n = s0 + w; n < s1; n += 4) {
      float v = feat[(size_t)n * 64 + l] * hhs[l];
#pragma unroll
      for (int off = 32; off; off >>= 1) v += __shfl_xor(v, off, 64);
      if (l == 0) ev[n] = v;
      mw = fmaxf(mw, v);
    }
    if (l == 0) redm[w] = mw;
    __syncthreads();
    float emax = fmaxf(fmaxf(redm[0], redm[1]), fmaxf(redm[2], redm[3]));
    float sd = 0.f;
    for (int n = s0 + t; n < s1; n += 256) sd += expf(ev[n] - emax);
    gates[t] = sd; __syncthreads();
    for (int off = 128; off; off >>= 1) { if (t < off) gates[t] += gates[t + off]; __syncthreads(); }
    float den = gates[0];
    __syncthreads();
    float pacc = 0.f;
    for (int n = s0 + w; n < s1; n += 4) {
      float a = expf(ev[n] - emax) / den;
      pacc += a * feat[(size_t)n * 64 + l];
    }
    part[w][l] = pacc; __syncthreads();
    if (t < 64) qs[64 + t] = part[0][t] + part[1][t] + part[2][t] + part[3][t];
    __syncthreads();
  }
  if (t < 128) outq[g * 128 + t] = qs[t];
}

// -------------------- feat part of output --------------------
__global__ void k_outf(const float* __restrict__ h, float* __restrict__ out) {
  int i = blockIdx.x * 256 + threadIdx.x;
  if (i < N_NODES * 64) out[B_GRAPHS * 128 + i] = h[i];
}

extern "C" void kernel_launch(void* const* d_in, const int* in_sizes, int n_in,
                              void* d_out, int out_size, void* d_ws, size_t ws_size,
                              hipStream_t stream) {
  (void)in_sizes; (void)n_in; (void)out_size;
  const float* x        = (const float*)d_in[0];
  const int*   ei       = (const int*)d_in[1];
  const int*   batch    = (const int*)d_in[2];
  const float* ea       = (const float*)d_in[3];
  const float* lin0_w   = (const float*)d_in[4];
  const float* lin0_b   = (const float*)d_in[5];
  const float* nn_w1    = (const float*)d_in[6];
  const float* nn_b1    = (const float*)d_in[7];
  const float* nn_w2    = (const float*)d_in[8];
  const float* nn_b2    = (const float*)d_in[9];
  const float* conv_b   = (const float*)d_in[10];
  const float* gru_w_ih = (const float*)d_in[11];
  const float* gru_w_hh = (const float*)d_in[12];
  const float* gru_b_ih = (const float*)d_in[13];
  const float* gru_b_hh = (const float*)d_in[14];
  const float* lstm_w_ih= (const float*)d_in[15];
  const float* lstm_w_hh= (const float*)d_in[16];
  const float* lstm_b_ih= (const float*)d_in[17];
  const float* lstm_b_hh= (const float*)d_in[18];
  const int* srcp = ei;
  const int* dstp = ei + N_EDGES;

  char* ws = (char*)d_ws;
  size_t off = 0;
  auto alloc = [&](size_t bytes) { void* p = ws + off; off += (bytes + 255) & ~(size_t)255; return p; };
  float* h     = (float*)alloc((size_t)N_NODES * 64 * 4);
  float* agg   = (float*)alloc((size_t)N_NODES * 64 * 4);
  float* deg   = (float*)alloc((size_t)N_NODES * 4);
  float* ev    = (float*)alloc((size_t)N_NODES * 4);
  int*   startv= (int*)alloc(65 * 4);
  int*   cnt   = (int*)alloc((size_t)N_NODES * 4);
  int*   starts= (int*)alloc((size_t)(N_NODES + 1) * 4);
  int*   ptr2  = (int*)alloc((size_t)N_NODES * 4);
  int*   eidx  = (int*)alloc((size_t)N_EDGES * 4);
  float* r1    = (float*)alloc((size_t)N_EDGES * HID * 4);
  u16*   w2qT  = (u16*)alloc((size_t)KTOT * 64 * 2);
  u16*   G     = (u16*)alloc((size_t)N_NODES * GSTRIDE * 2);
  bool useG = (ws_size >= off);

  hipMemsetAsync(deg, 0, (size_t)N_NODES * 4, stream);

  k_lin0<<<(N_NODES + 3) / 4, 256, 0, stream>>>(x, lin0_w, lin0_b, h);
  k_deg<<<(N_EDGES + 255) / 256, 256, 0, stream>>>(dstp, deg);
  k_bounds<<<1, 128, 0, stream>>>(batch, startv);

  if (useG) {
    hipMemsetAsync(cnt, 0, (size_t)N_NODES * 4, stream);
    k_cnt<<<(N_EDGES + 255) / 256, 256, 0, stream>>>(srcp, cnt);
    k_scan<<<1, 256, 0, stream>>>(cnt, starts, ptr2);
    k_place<<<(N_EDGES + 255) / 256, 256, 0, stream>>>(srcp, ptr2, eidx);
    k_r1<<<N_EDGES, HID, 0, stream>>>(ea, nn_w1, nn_b1, r1);
    k_w2p<<<(KTOT * 64 + 255) / 256, 256, 0, stream>>>(nn_w2, nn_b2, w2qT);
    for (int it = 0; it < 3; ++it) {
      hipMemsetAsync(agg, 0, (size_t)N_NODES * 64 * 4, stream);
      k_Gm<<<dim3((N_NODES + 63) / 64, (KTOT + 255) / 256), 256, 0, stream>>>(h, w2qT, G);
      k_msg3<<<N_NODES, 256, 0, stream>>>(starts, eidx, dstp, r1, G, agg);
      k_gru2<<<(N_NODES + GNB - 1) / GNB, 256, 0, stream>>>(agg, deg, conv_b, gru_w_ih, gru_w_hh,
                                                            gru_b_ih, gru_b_hh, h);
    }
  } else {
    for (int it = 0; it < 3; ++it) {
      hipMemsetAsync(agg, 0, (size_t)N_NODES * 64 * 4, stream);
      k_msgv<<<dim3(313, KY_SPLIT), 256, 0, stream>>>(srcp, dstp, h, ea, nn_w1, nn_b1,
                                                      nn_w2, nn_b2, agg);
      k_gru2<<<(N_NODES + GNB - 1) / GNB, 256, 0, stream>>>(agg, deg, conv_b, gru_w_ih, gru_w_hh,
                                                            gru_b_ih, gru_b_hh, h);
    }
  }

  k_s2s<<<B_GRAPHS, 256, 0, stream>>>(lstm_w_ih, lstm_w_hh, lstm_b_ih, lstm_b_hh,
                                      h, startv, ev, (float*)d_out);
  k_outf<<<(N_NODES * 64 + 255) / 256, 256, 0, stream>>>(h, (float*)d_out);
}

// Round 12
// 406.784 us; speedup vs baseline: 8.5164x; 1.0862x over previous
//
#include <hip/hip_runtime.h>

#define N_NODES 5000
#define N_EDGES 20000
#define B_GRAPHS 64
#define DD 64
#define HID 128
#define EDGE_FEAT 5
#define KTOT 8256   // 8192 + 64 bias cols
#define GSTRIDE 8256
#define KY_SPLIT 8
#define KCHUNK 1032
#define GNB 16      // nodes per k_gru2 block

typedef unsigned short u16;
typedef float f32x4 __attribute__((ext_vector_type(4)));
typedef u16 u16x8 __attribute__((ext_vector_type(8)));
typedef __bf16 bf16x8 __attribute__((ext_vector_type(8)));
union AB { u16x8 u; bf16x8 b; };

__device__ __forceinline__ float b2f(u16 u) {
  union { unsigned u32; float f; } v; v.u32 = ((unsigned)u) << 16; return v.f;
}
__device__ __forceinline__ u16 f2b(float f) {
  union { float f; unsigned u; } v; v.f = f;
  unsigned r = v.u + 0x7FFF + ((v.u >> 16) & 1);
  return (u16)(r >> 16);
}
__device__ __forceinline__ float sigf(float x) { return 1.f / (1.f + expf(-x)); }

// -------------------- lin0: h = relu(x @ W + b), 4 nodes/block --------------------
__global__ __launch_bounds__(256) void k_lin0(const float* __restrict__ x, const float* __restrict__ w,
                       const float* __restrict__ b, float* __restrict__ h) {
  __shared__ float xs[4][64];
  int wv = threadIdx.x >> 6, j = threadIdx.x & 63;
  int n = blockIdx.x * 4 + wv;
  if (n >= N_NODES) return;
  xs[wv][j] = x[(size_t)n * 64 + j];
  __syncthreads();
  float acc = b[j];
#pragma unroll
  for (int i = 0; i < 64; ++i) acc += xs[wv][i] * w[i * 64 + j];
  h[(size_t)n * 64 + j] = fmaxf(acc, 0.f);
}

// -------------------- deg (dst) + CSR count (src) in one pass --------------------
__global__ void k_degcnt(const int* __restrict__ src, const int* __restrict__ dst,
                         float* __restrict__ deg, int* __restrict__ cnt) {
  int e = blockIdx.x * 256 + threadIdx.x;
  if (e < N_EDGES) {
    atomicAdd(&deg[dst[e]], 1.0f);
    atomicAdd(&cnt[src[e]], 1);
  }
}

// -------------------- CSR: block-wide exclusive scan over 5000 --------------------
__global__ void k_scan(const int* __restrict__ cnt, int* __restrict__ starts,
                       int* __restrict__ ptr2) {
  __shared__ int buf[256];
  __shared__ int carry;
  int t = threadIdx.x;
  if (t == 0) carry = 0;
  __syncthreads();
  for (int base = 0; base < N_NODES; base += 256) {
    int v = (base + t < N_NODES) ? cnt[base + t] : 0;
    buf[t] = v;
    __syncthreads();
    for (int off = 1; off < 256; off <<= 1) {
      int add = (t >= off) ? buf[t - off] : 0;
      __syncthreads();
      buf[t] += add;
      __syncthreads();
    }
    if (base + t < N_NODES) {
      int excl = carry + buf[t] - v;
      starts[base + t] = excl;
      ptr2[base + t] = excl;
    }
    __syncthreads();
    if (t == 0) carry += buf[255];
    __syncthreads();
  }
  if (t == 0) starts[N_NODES] = carry;
}

// -------------------- CSR: place edge ids --------------------
__global__ void k_place(const int* __restrict__ src, int* __restrict__ ptr2,
                        int* __restrict__ eidx) {
  int e = blockIdx.x * 256 + threadIdx.x;
  if (e < N_EDGES) {
    int pos = atomicAdd(&ptr2[src[e]], 1);
    eidx[pos] = e;
  }
}

// -------------------- graph boundaries in sorted batch --------------------
__global__ void k_bounds(const int* __restrict__ batch, int* __restrict__ start) {
  int g = threadIdx.x;
  if (g > B_GRAPHS) return;
  int lo = 0, hi = N_NODES;
  while (lo < hi) { int mid = (lo + hi) >> 1; if (batch[mid] < g) lo = mid + 1; else hi = mid; }
  start[g] = lo;
}

// -------------------- r1 = relu(edge_attr @ W1 + b1), 2 edges/block ----------
__global__ __launch_bounds__(256) void k_r1b(const float* __restrict__ ea, const float* __restrict__ w1,
                      const float* __restrict__ b1, float* __restrict__ r1) {
  __shared__ float a[2][EDGE_FEAT];
  int t = threadIdx.x;
  int e0 = blockIdx.x * 2;
  if (t < 2 * EDGE_FEAT) a[t / EDGE_FEAT][t % EDGE_FEAT] = ea[(size_t)e0 * EDGE_FEAT + t];
  __syncthreads();
  int sub = t >> 7, c = t & 127;
  float acc = b1[c];
#pragma unroll
  for (int k = 0; k < EDGE_FEAT; ++k) acc += a[sub][k] * w1[k * HID + c];
  r1[(size_t)(e0 + sub) * HID + c] = fmaxf(acc, 0.f);
}

// ---------- w2qT transpose via LDS: w2qT[(kp*64+o)*64+i] = bf16(w2[kp][i*64+o]) ----------
// Block per kp (129 = 128 w2-rows + 1 bias row from b2).
__global__ __launch_bounds__(256) void k_w2pT(const float* __restrict__ w2, const float* __restrict__ b2,
                       u16* __restrict__ w2qT) {
  __shared__ float tile[64][65];   // [o][i]
  int kp = blockIdx.x, t = threadIdx.x;
  const float* srcp = (kp < 128) ? (w2 + (size_t)kp * 4096) : b2;
#pragma unroll
  for (int ch = 0; ch < 16; ++ch) {
    int idx = ch * 256 + t;        // = i*64+o
    tile[idx & 63][idx >> 6] = srcp[idx];
  }
  __syncthreads();
  // write: thread t covers o = t>>2, i0 = (t&3)*16
  int o = t >> 2, i0 = (t & 3) * 16;
  u16x8 p0, p1;
#pragma unroll
  for (int j = 0; j < 8; ++j) { p0[j] = f2b(tile[o][i0 + j]); p1[j] = f2b(tile[o][i0 + 8 + j]); }
  u16* dst = w2qT + ((size_t)kp * 64 + o) * 64 + i0;
  *(u16x8*)dst = p0;
  *(u16x8*)(dst + 8) = p1;
}

// -------------------- G = h @ W2q via MFMA bf16; G stored bf16 --------------------
// 64 rows x 256 cols/block; B-fragments prefetched to VGPRs; vectorized staging.
__global__ __launch_bounds__(256) void k_Gm(const float* __restrict__ h,
                                            const u16* __restrict__ w2qT,
                                            u16* __restrict__ G) {
  __shared__ u16 hsb[64][72];
  __shared__ u16 outs[64][266];   // dword-stride 133 (≡5 mod 32) – conflict-spread
  int row0 = blockIdx.x * 64, c0 = blockIdx.y * 256;
  int t = threadIdx.x, w = t >> 6, lane = t & 63;

  {
    int r = t >> 2, qp = t & 3;
    int row = row0 + r;
    u16x8 p0 = {0,0,0,0,0,0,0,0}, p1 = {0,0,0,0,0,0,0,0};
    if (row < N_NODES) {
      const f32x4* hp = (const f32x4*)(h + (size_t)row * 64 + qp * 16);
      f32x4 v0 = hp[0], v1 = hp[1], v2 = hp[2], v3 = hp[3];
      p0[0]=f2b(v0.x); p0[1]=f2b(v0.y); p0[2]=f2b(v0.z); p0[3]=f2b(v0.w);
      p0[4]=f2b(v1.x); p0[5]=f2b(v1.y); p0[6]=f2b(v1.z); p0[7]=f2b(v1.w);
      p1[0]=f2b(v2.x); p1[1]=f2b(v2.y); p1[2]=f2b(v2.z); p1[3]=f2b(v2.w);
      p1[4]=f2b(v3.x); p1[5]=f2b(v3.y); p1[6]=f2b(v3.z); p1[7]=f2b(v3.w);
    }
    *(u16x8*)&hsb[r][qp * 16] = p0;
    *(u16x8*)&hsb[r][qp * 16 + 8] = p1;
  }
  __syncthreads();

  // prefetch all 8 B fragments (2 ks x 4 ct) — independent L2 loads in flight
  AB bfr[2][4];
#pragma unroll
  for (int ks = 0; ks < 2; ++ks)
#pragma unroll
    for (int ct = 0; ct < 4; ++ct) {
      int c = c0 + w * 64 + ct * 16 + (lane & 15);
      int kb = ks * 32 + (lane >> 4) * 8;
      if (c < KTOT) bfr[ks][ct].u = *(const u16x8*)(w2qT + (size_t)c * 64 + kb);
      else bfr[ks][ct].u = (u16x8){0,0,0,0,0,0,0,0};
    }
  // A fragments from LDS
  AB afr[2][4];
#pragma unroll
  for (int ks = 0; ks < 2; ++ks)
#pragma unroll
    for (int rt = 0; rt < 4; ++rt)
      afr[ks][rt].u = *(const u16x8*)&hsb[rt * 16 + (lane & 15)][ks * 32 + (lane >> 4) * 8];

  f32x4 acc[4][4];
#pragma unroll
  for (int rt = 0; rt < 4; ++rt)
#pragma unroll
    for (int ct = 0; ct < 4; ++ct) acc[rt][ct] = (f32x4){0.f, 0.f, 0.f, 0.f};

#pragma unroll
  for (int ks = 0; ks < 2; ++ks)
#pragma unroll
    for (int ct = 0; ct < 4; ++ct)
#pragma unroll
      for (int rt = 0; rt < 4; ++rt)
        acc[rt][ct] = __builtin_amdgcn_mfma_f32_16x16x32_bf16(afr[ks][rt].b, bfr[ks][ct].b, acc[rt][ct], 0, 0, 0);

#pragma unroll
  for (int rt = 0; rt < 4; ++rt)
#pragma unroll
    for (int ct = 0; ct < 4; ++ct) {
      int lcol = w * 64 + ct * 16 + (lane & 15);
      int lrow0 = rt * 16 + (lane >> 4) * 4;
#pragma unroll
      for (int r = 0; r < 4; ++r) outs[lrow0 + r][lcol] = f2b(acc[rt][ct][r]);
    }
  __syncthreads();

  {
    int r2 = t & 63, seg = t >> 6;     // lane=row → LDS read 2-way (free)
    int row = row0 + r2;
    if (row < N_NODES) {
#pragma unroll
      for (int i = 0; i < 8; ++i) {
        int c = seg * 64 + i * 8;
        int gc = c0 + c;
        if (gc < KTOT)
          *(u16x8*)(G + (size_t)row * GSTRIDE + gc) = *(const u16x8*)&outs[r2][c];
      }
    }
  }
}

// -------------------- msg3: CSR-by-src, G row staged in LDS --------------------
__global__ __launch_bounds__(256) void k_msg3(const int* __restrict__ starts,
                                              const int* __restrict__ eidx,
                                              const int* __restrict__ dst,
                                              const float* __restrict__ r1,
                                              const u16* __restrict__ G,
                                              float* __restrict__ agg) {
  __shared__ u16 grow[128 * 64];
  __shared__ float gbias[64];
  __shared__ float r1e[128];
  __shared__ float part[4][64];
  int s = blockIdx.x;
  int e0 = starts[s], e1 = starts[s + 1];
  if (e0 >= e1) return;
  int t = threadIdx.x, w = t >> 6, l = t & 63;

  const u16* Gs = G + (size_t)s * GSTRIDE;
#pragma unroll
  for (int i = 0; i < 4; ++i)
    *(u16x8*)(grow + t * 8 + i * 2048) = *(const u16x8*)(Gs + t * 8 + i * 2048);
  if (t < 64) gbias[t] = b2f(Gs[8192 + t]);
  __syncthreads();

  for (int ei = e0; ei < e1; ++ei) {
    int e = eidx[ei];
    if (t < 128) r1e[t] = r1[(size_t)e * HID + t];
    __syncthreads();
    float acc = 0.f;
    const u16* gw = grow + w * 32 * 64 + l;
#pragma unroll 8
    for (int kap = 0; kap < 32; ++kap)
      acc += r1e[w * 32 + kap] * b2f(gw[kap * 64]);
    part[w][l] = acc;
    __syncthreads();
    if (t < 64) {
      float v = part[0][l] + part[1][l] + part[2][l] + part[3][l] + gbias[l];
      atomicAdd(&agg[(size_t)dst[e] * 64 + l], v);
    }
    __syncthreads();
  }
}

// -------------------- fallback: fused msg (VALU; r1 recomputed in-block) ----------
__global__ __launch_bounds__(256) void k_msgv(const int* __restrict__ src,
                                              const int* __restrict__ dst,
                                              const float* __restrict__ h,
                                              const float* __restrict__ ea,
                                              const float* __restrict__ w1,
                                              const float* __restrict__ b1,
                                              const float* __restrict__ w2,
                                              const float* __restrict__ b2,
                                              float* __restrict__ agg) {
  __shared__ float hs[64][68];
  __shared__ float r1sv[64][132];
  __shared__ float w1s[EDGE_FEAT][HID];
  __shared__ float b1s[HID];
  __shared__ float eas[64][EDGE_FEAT];
  __shared__ int dsts[64];

  int bm = blockIdx.x, ky = blockIdx.y;
  int t = threadIdx.x;
  int wave = t >> 6, lane = t & 63;

  if (t < HID) b1s[t] = b1[t];
  for (int i = t; i < EDGE_FEAT * HID; i += 256) w1s[i / HID][i % HID] = w1[i];
  {
    int r = t >> 2, qp = t & 3;
    int e = bm * 64 + r;
    if (t < 64) dsts[t] = (bm * 64 + t < N_EDGES) ? dst[bm * 64 + t] : -1;
    if (e < N_EDGES) {
      int s = src[e];
#pragma unroll
      for (int i = 0; i < 16; ++i) hs[r][qp * 16 + i] = h[(size_t)s * 64 + qp * 16 + i];
      if (qp == 0)
#pragma unroll
        for (int k = 0; k < EDGE_FEAT; ++k) eas[r][k] = ea[(size_t)e * EDGE_FEAT + k];
    } else {
#pragma unroll
      for (int i = 0; i < 16; ++i) hs[r][qp * 16 + i] = 0.f;
      if (qp == 0)
#pragma unroll
        for (int k = 0; k < EDGE_FEAT; ++k) eas[r][k] = 0.f;
    }
  }
  __syncthreads();

  for (int idx = t; idx < 64 * HID; idx += 256) {
    int rr = idx >> 7, c = idx & 127;
    float acc = b1s[c];
#pragma unroll
    for (int k = 0; k < EDGE_FEAT; ++k) acc += eas[rr][k] * w1s[k][c];
    r1sv[rr][c] = fmaxf(acc, 0.f);
  }
  if (t < 64) r1sv[t][128] = 1.0f;
  __syncthreads();

  int row0 = wave * 16 + (lane >> 4) * 4;
  int colb = lane & 15;

  float acc[4][4];
#pragma unroll
  for (int ct = 0; ct < 4; ++ct)
#pragma unroll
    for (int r = 0; r < 4; ++r) acc[ct][r] = 0.f;

  int k0 = ky * KCHUNK, k1 = k0 + KCHUNK;
  for (int kp = k0; kp < k1; ++kp) {
    int kap = kp >> 6, ii = kp & 63;
    const float* Bp = (kp < 8192) ? (w2 + (size_t)kp * 64)
                                  : (b2 + (size_t)(kp - 8192) * 64);
    float bv[4];
#pragma unroll
    for (int ct = 0; ct < 4; ++ct) bv[ct] = Bp[ct * 16 + colb];
#pragma unroll
    for (int r = 0; r < 4; ++r) {
      float a = r1sv[row0 + r][kap] * hs[row0 + r][ii];
#pragma unroll
      for (int ct = 0; ct < 4; ++ct) acc[ct][r] += a * bv[ct];
    }
  }

#pragma unroll
  for (int ct = 0; ct < 4; ++ct) {
    int col = ct * 16 + colb;
#pragma unroll
    for (int r = 0; r < 4; ++r) {
      int dd = dsts[row0 + r];
      if (dd >= 0) atomicAdd(&agg[(size_t)dd * 64 + col], acc[ct][r]);
    }
  }
}

// ---------- GRU step, 16 nodes/block, weights in VGPRs; zeroes agg; optional out-write ----------
__global__ __launch_bounds__(256) void k_gru2(const float* __restrict__ agg_in, const float* __restrict__ deg,
                                              const float* __restrict__ conv_b,
                                              const float* __restrict__ wih, const float* __restrict__ whh,
                                              const float* __restrict__ bih, const float* __restrict__ bhh,
                                              float* __restrict__ h, float* __restrict__ agg_clr,
                                              float* __restrict__ outp) {
  __shared__ float ms[GNB][64], hsn[GNB][64];
  __shared__ float gis[GNB][192], ghs[GNB][192];
  int n0 = blockIdx.x * GNB;
  int t = threadIdx.x;

  for (int idx = t; idx < GNB * 64; idx += 256) {
    int r = idx >> 6, c = idx & 63;
    int n = n0 + r;
    if (n < N_NODES) {
      float dg = fmaxf(deg[n], 1.0f);
      ms[r][c] = fmaxf(agg_in[(size_t)n * 64 + c] / dg + conv_b[c], 0.f);
      hsn[r][c] = h[(size_t)n * 64 + c];
      agg_clr[(size_t)n * 64 + c] = 0.f;   // re-zero for next iteration
    } else { ms[r][c] = 0.f; hsn[r][c] = 0.f; }
  }
  __syncthreads();

  if (t < 192) {
    f32x4 wr[16];
    const f32x4* wp = (const f32x4*)(wih + (size_t)t * 64);
#pragma unroll
    for (int i = 0; i < 16; ++i) wr[i] = wp[i];
    float bi = bih[t];
    for (int n = 0; n < GNB; ++n) {
      float acc = bi;
#pragma unroll
      for (int i = 0; i < 16; ++i) {
        f32x4 v = wr[i];
        acc += ms[n][4*i] * v.x + ms[n][4*i+1] * v.y + ms[n][4*i+2] * v.z + ms[n][4*i+3] * v.w;
      }
      gis[n][t] = acc;
    }
    const f32x4* hp = (const f32x4*)(whh + (size_t)t * 64);
#pragma unroll
    for (int i = 0; i < 16; ++i) wr[i] = hp[i];
    float bh = bhh[t];
    for (int n = 0; n < GNB; ++n) {
      float acc = bh;
#pragma unroll
      for (int i = 0; i < 16; ++i) {
        f32x4 v = wr[i];
        acc += hsn[n][4*i] * v.x + hsn[n][4*i+1] * v.y + hsn[n][4*i+2] * v.z + hsn[n][4*i+3] * v.w;
      }
      ghs[n][t] = acc;
    }
  }
  __syncthreads();

  for (int idx = t; idx < GNB * 64; idx += 256) {
    int rr = idx >> 6, c = idx & 63;
    int n = n0 + rr;
    if (n < N_NODES) {
      float r = sigf(gis[rr][c] + ghs[rr][c]);
      float z = sigf(gis[rr][64 + c] + ghs[rr][64 + c]);
      float nn = tanhf(gis[rr][128 + c] + r * ghs[rr][128 + c]);
      float hv = (1.f - z) * nn + z * hsn[rr][c];
      h[(size_t)n * 64 + c] = hv;
      if (outp) outp[B_GRAPHS * 128 + (size_t)n * 64 + c] = hv;
    }
  }
}

// -------------------- fused Set2Set: 1 block per graph, 3 steps in-kernel ----------
__global__ __launch_bounds__(256) void k_s2s(const float* __restrict__ wih, const float* __restrict__ whh,
                                             const float* __restrict__ bih, const float* __restrict__ bhh,
                                             const float* __restrict__ feat, const int* __restrict__ start,
                                             float* __restrict__ ev, float* __restrict__ outq) {
  __shared__ float qs[128], hhs[64], ccs[64], gates[256], part[4][64], redm[4];
  int g = blockIdx.x, t = threadIdx.x, w = t >> 6, l = t & 63;
  int s0 = start[g], s1 = start[g + 1];
  if (t < 128) qs[t] = 0.f;
  if (t < 64) { hhs[t] = 0.f; ccs[t] = 0.f; }
  __syncthreads();

  for (int step = 0; step < 3; ++step) {
    {
      float acc = bih[t] + bhh[t];
      const f32x4* wr = (const f32x4*)(wih + (size_t)t * 128);
#pragma unroll
      for (int i = 0; i < 32; ++i) {
        f32x4 v = wr[i];
        acc += qs[4 * i] * v.x + qs[4 * i + 1] * v.y + qs[4 * i + 2] * v.z + qs[4 * i + 3] * v.w;
      }
      const f32x4* hr = (const f32x4*)(whh + (size_t)t * 64);
#pragma unroll
      for (int i = 0; i < 16; ++i) {
        f32x4 v = hr[i];
        acc += hhs[4 * i] * v.x + hhs[4 * i + 1] * v.y + hhs[4 * i + 2] * v.z + hhs[4 * i + 3] * v.w;
      }
      gates[t] = acc;
    }
    __syncthreads();
    if (t < 64) {
      float c_new = sigf(gates[64 + t]) * ccs[t] + sigf(gates[t]) * tanhf(gates[128 + t]);
      hhs[t] = sigf(gates[192 + t]) * tanhf(c_new);
      ccs[t] = c_new;
      qs[t] = hhs[t];
    }
    __syncthreads();

    float mw = -1e30f;
    for (int n = s0 + w; n < s1; n += 4) {
      float v = feat[(size_t)n * 64 + l] * hhs[l];
#pragma unroll
      for (int off = 32; off; off >>= 1) v += __shfl_xor(v, off, 64);
      if (l == 0) ev[n] = v;
      mw = fmaxf(mw, v);
    }
    if (l == 0) redm[w] = mw;
    __syncthreads();
    float emax = fmaxf(fmaxf(redm[0], redm[1]), fmaxf(redm[2], redm[3]));
    float sd = 0.f;
    for (int n = s0 + t; n < s1; n += 256) sd += expf(ev[n] - emax);
    gates[t] = sd; __syncthreads();
    for (int off = 128; off; off >>= 1) { if (t < off) gates[t] += gates[t + off]; __syncthreads(); }
    float den = gates[0];
    __syncthreads();
    float pacc = 0.f;
    for (int n = s0 + w; n < s1; n += 4) {
      float a = expf(ev[n] - emax) / den;
      pacc += a * feat[(size_t)n * 64 + l];
    }
    part[w][l] = pacc; __syncthreads();
    if (t < 64) qs[64 + t] = part[0][t] + part[1][t] + part[2][t] + part[3][t];
    __syncthreads();
  }
  if (t < 128) outq[g * 128 + t] = qs[t];
}

extern "C" void kernel_launch(void* const* d_in, const int* in_sizes, int n_in,
                              void* d_out, int out_size, void* d_ws, size_t ws_size,
                              hipStream_t stream) {
  (void)in_sizes; (void)n_in; (void)out_size;
  const float* x        = (const float*)d_in[0];
  const int*   ei       = (const int*)d_in[1];
  const int*   batch    = (const int*)d_in[2];
  const float* ea       = (const float*)d_in[3];
  const float* lin0_w   = (const float*)d_in[4];
  const float* lin0_b   = (const float*)d_in[5];
  const float* nn_w1    = (const float*)d_in[6];
  const float* nn_b1    = (const float*)d_in[7];
  const float* nn_w2    = (const float*)d_in[8];
  const float* nn_b2    = (const float*)d_in[9];
  const float* conv_b   = (const float*)d_in[10];
  const float* gru_w_ih = (const float*)d_in[11];
  const float* gru_w_hh = (const float*)d_in[12];
  const float* gru_b_ih = (const float*)d_in[13];
  const float* gru_b_hh = (const float*)d_in[14];
  const float* lstm_w_ih= (const float*)d_in[15];
  const float* lstm_w_hh= (const float*)d_in[16];
  const float* lstm_b_ih= (const float*)d_in[17];
  const float* lstm_b_hh= (const float*)d_in[18];
  const int* srcp = ei;
  const int* dstp = ei + N_EDGES;

  char* ws = (char*)d_ws;
  size_t off = 0;
  auto alloc = [&](size_t bytes) { void* p = ws + off; off += (bytes + 255) & ~(size_t)255; return p; };
  float* h     = (float*)alloc((size_t)N_NODES * 64 * 4);
  float* agg   = (float*)alloc((size_t)N_NODES * 64 * 4);
  float* deg   = (float*)alloc((size_t)N_NODES * 4);
  float* ev    = (float*)alloc((size_t)N_NODES * 4);
  int*   startv= (int*)alloc(65 * 4);
  int*   cnt   = (int*)alloc((size_t)N_NODES * 4);
  int*   starts= (int*)alloc((size_t)(N_NODES + 1) * 4);
  int*   ptr2  = (int*)alloc((size_t)N_NODES * 4);
  int*   eidx  = (int*)alloc((size_t)N_EDGES * 4);
  float* r1    = (float*)alloc((size_t)N_EDGES * HID * 4);
  u16*   w2qT  = (u16*)alloc((size_t)KTOT * 64 * 2);
  u16*   G     = (u16*)alloc((size_t)N_NODES * GSTRIDE * 2);
  bool useG = (ws_size >= off);

  hipMemsetAsync(deg, 0, (size_t)N_NODES * 4, stream);
  hipMemsetAsync(agg, 0, (size_t)N_NODES * 64 * 4, stream);

  k_lin0<<<(N_NODES + 3) / 4, 256, 0, stream>>>(x, lin0_w, lin0_b, h);
  k_bounds<<<1, 128, 0, stream>>>(batch, startv);

  if (useG) {
    hipMemsetAsync(cnt, 0, (size_t)N_NODES * 4, stream);
    k_degcnt<<<(N_EDGES + 255) / 256, 256, 0, stream>>>(srcp, dstp, deg, cnt);
    k_scan<<<1, 256, 0, stream>>>(cnt, starts, ptr2);
    k_place<<<(N_EDGES + 255) / 256, 256, 0, stream>>>(srcp, ptr2, eidx);
    k_r1b<<<N_EDGES / 2, 256, 0, stream>>>(ea, nn_w1, nn_b1, r1);
    k_w2pT<<<129, 256, 0, stream>>>(nn_w2, nn_b2, w2qT);
    for (int it = 0; it < 3; ++it) {
      k_Gm<<<dim3((N_NODES + 63) / 64, (KTOT + 255) / 256), 256, 0, stream>>>(h, w2qT, G);
      k_msg3<<<N_NODES, 256, 0, stream>>>(starts, eidx, dstp, r1, G, agg);
      k_gru2<<<(N_NODES + GNB - 1) / GNB, 256, 0, stream>>>(agg, deg, conv_b, gru_w_ih, gru_w_hh,
                                                            gru_b_ih, gru_b_hh, h, agg,
                                                            (it == 2) ? (float*)d_out : nullptr);
    }
  } else {
    hipMemsetAsync(cnt, 0, (size_t)N_NODES * 4, stream);
    k_degcnt<<<(N_EDGES + 255) / 256, 256, 0, stream>>>(srcp, dstp, deg, cnt);
    for (int it = 0; it < 3; ++it) {
      k_msgv<<<dim3(313, KY_SPLIT), 256, 0, stream>>>(srcp, dstp, h, ea, nn_w1, nn_b1,
                                                      nn_w2, nn_b2, agg);
      k_gru2<<<(N_NODES + GNB - 1) / GNB, 256, 0, stream>>>(agg, deg, conv_b, gru_w_ih, gru_w_hh,
                                                            gru_b_ih, gru_b_hh, h, agg,
                                                            (it == 2) ? (float*)d_out : nullptr);
    }
  }

  k_s2s<<<B_GRAPHS, 256, 0, stream>>>(lstm_w_ih, lstm_w_hh, lstm_b_ih, lstm_b_hh,
                                      h, startv, ev, (float*)d_out);
}

// Round 13
// 378.462 us; speedup vs baseline: 9.1538x; 1.0748x over previous
//
#include <hip/hip_runtime.h>

#define N_NODES 5000
#define N_EDGES 20000
#define B_GRAPHS 64
#define DD 64
#define HID 128
#define EDGE_FEAT 5
#define KTOT 8256   // 8192 + 64 bias cols
#define GSTRIDE 8256
#define KY_SPLIT 8
#define KCHUNK 1032
#define GNB 16      // nodes per k_gru2 block
#define S2SCAP 160  // cached nodes/graph in k_s2s (mean 78, max ~110)

typedef unsigned short u16;
typedef float f32x4 __attribute__((ext_vector_type(4)));
typedef u16 u16x8 __attribute__((ext_vector_type(8)));
typedef __bf16 bf16x8 __attribute__((ext_vector_type(8)));
union AB { u16x8 u; bf16x8 b; };

__device__ __forceinline__ float b2f(u16 u) {
  union { unsigned u32; float f; } v; v.u32 = ((unsigned)u) << 16; return v.f;
}
__device__ __forceinline__ u16 f2b(float f) {
  union { float f; unsigned u; } v; v.f = f;
  unsigned r = v.u + 0x7FFF + ((v.u >> 16) & 1);
  return (u16)(r >> 16);
}
__device__ __forceinline__ float sigf(float x) { return 1.f / (1.f + expf(-x)); }

// -------------------- lin0: h = relu(x @ W + b), 4 nodes/block --------------------
__global__ __launch_bounds__(256) void k_lin0(const float* __restrict__ x, const float* __restrict__ w,
                       const float* __restrict__ b, float* __restrict__ h) {
  __shared__ float xs[4][64];
  int wv = threadIdx.x >> 6, j = threadIdx.x & 63;
  int n = blockIdx.x * 4 + wv;
  if (n >= N_NODES) return;
  xs[wv][j] = x[(size_t)n * 64 + j];
  __syncthreads();
  float acc = b[j];
#pragma unroll
  for (int i = 0; i < 64; ++i) acc += xs[wv][i] * w[i * 64 + j];
  h[(size_t)n * 64 + j] = fmaxf(acc, 0.f);
}

// -------------------- deg (dst) + CSR count (src) in one pass --------------------
__global__ void k_degcnt(const int* __restrict__ src, const int* __restrict__ dst,
                         float* __restrict__ deg, int* __restrict__ cnt) {
  int e = blockIdx.x * 256 + threadIdx.x;
  if (e < N_EDGES) {
    atomicAdd(&deg[dst[e]], 1.0f);
    atomicAdd(&cnt[src[e]], 1);
  }
}

// -------------------- CSR: block-wide exclusive scan over 5000 --------------------
__global__ void k_scan(const int* __restrict__ cnt, int* __restrict__ starts,
                       int* __restrict__ ptr2) {
  __shared__ int buf[256];
  __shared__ int carry;
  int t = threadIdx.x;
  if (t == 0) carry = 0;
  __syncthreads();
  for (int base = 0; base < N_NODES; base += 256) {
    int v = (base + t < N_NODES) ? cnt[base + t] : 0;
    buf[t] = v;
    __syncthreads();
    for (int off = 1; off < 256; off <<= 1) {
      int add = (t >= off) ? buf[t - off] : 0;
      __syncthreads();
      buf[t] += add;
      __syncthreads();
    }
    if (base + t < N_NODES) {
      int excl = carry + buf[t] - v;
      starts[base + t] = excl;
      ptr2[base + t] = excl;
    }
    __syncthreads();
    if (t == 0) carry += buf[255];
    __syncthreads();
  }
  if (t == 0) starts[N_NODES] = carry;
}

// -------------------- CSR: place edge ids --------------------
__global__ void k_place(const int* __restrict__ src, int* __restrict__ ptr2,
                        int* __restrict__ eidx) {
  int e = blockIdx.x * 256 + threadIdx.x;
  if (e < N_EDGES) {
    int pos = atomicAdd(&ptr2[src[e]], 1);
    eidx[pos] = e;
  }
}

// -------------------- graph boundaries in sorted batch --------------------
__global__ void k_bounds(const int* __restrict__ batch, int* __restrict__ start) {
  int g = threadIdx.x;
  if (g > B_GRAPHS) return;
  int lo = 0, hi = N_NODES;
  while (lo < hi) { int mid = (lo + hi) >> 1; if (batch[mid] < g) lo = mid + 1; else hi = mid; }
  start[g] = lo;
}

// -------------------- r1 = relu(edge_attr @ W1 + b1), 2 edges/block ----------
__global__ __launch_bounds__(256) void k_r1b(const float* __restrict__ ea, const float* __restrict__ w1,
                      const float* __restrict__ b1, float* __restrict__ r1) {
  __shared__ float a[2][EDGE_FEAT];
  int t = threadIdx.x;
  int e0 = blockIdx.x * 2;
  if (t < 2 * EDGE_FEAT) a[t / EDGE_FEAT][t % EDGE_FEAT] = ea[(size_t)e0 * EDGE_FEAT + t];
  __syncthreads();
  int sub = t >> 7, c = t & 127;
  float acc = b1[c];
#pragma unroll
  for (int k = 0; k < EDGE_FEAT; ++k) acc += a[sub][k] * w1[k * HID + c];
  r1[(size_t)(e0 + sub) * HID + c] = fmaxf(acc, 0.f);
}

// ---------- w2qT transpose via LDS ----------
__global__ __launch_bounds__(256) void k_w2pT(const float* __restrict__ w2, const float* __restrict__ b2,
                       u16* __restrict__ w2qT) {
  __shared__ float tile[64][65];   // [o][i]
  int kp = blockIdx.x, t = threadIdx.x;
  const float* srcp = (kp < 128) ? (w2 + (size_t)kp * 4096) : b2;
#pragma unroll
  for (int ch = 0; ch < 16; ++ch) {
    int idx = ch * 256 + t;        // = i*64+o
    tile[idx & 63][idx >> 6] = srcp[idx];
  }
  __syncthreads();
  int o = t >> 2, i0 = (t & 3) * 16;
  u16x8 p0, p1;
#pragma unroll
  for (int j = 0; j < 8; ++j) { p0[j] = f2b(tile[o][i0 + j]); p1[j] = f2b(tile[o][i0 + 8 + j]); }
  u16* dst = w2qT + ((size_t)kp * 64 + o) * 64 + i0;
  *(u16x8*)dst = p0;
  *(u16x8*)(dst + 8) = p1;
}

// -------------------- G = h @ W2q via MFMA bf16; G stored bf16 --------------------
__global__ __launch_bounds__(256) void k_Gm(const float* __restrict__ h,
                                            const u16* __restrict__ w2qT,
                                            u16* __restrict__ G) {
  __shared__ u16 hsb[64][72];
  __shared__ u16 outs[64][266];
  int row0 = blockIdx.x * 64, c0 = blockIdx.y * 256;
  int t = threadIdx.x, w = t >> 6, lane = t & 63;

  {
    int r = t >> 2, qp = t & 3;
    int row = row0 + r;
    u16x8 p0 = {0,0,0,0,0,0,0,0}, p1 = {0,0,0,0,0,0,0,0};
    if (row < N_NODES) {
      const f32x4* hp = (const f32x4*)(h + (size_t)row * 64 + qp * 16);
      f32x4 v0 = hp[0], v1 = hp[1], v2 = hp[2], v3 = hp[3];
      p0[0]=f2b(v0.x); p0[1]=f2b(v0.y); p0[2]=f2b(v0.z); p0[3]=f2b(v0.w);
      p0[4]=f2b(v1.x); p0[5]=f2b(v1.y); p0[6]=f2b(v1.z); p0[7]=f2b(v1.w);
      p1[0]=f2b(v2.x); p1[1]=f2b(v2.y); p1[2]=f2b(v2.z); p1[3]=f2b(v2.w);
      p1[4]=f2b(v3.x); p1[5]=f2b(v3.y); p1[6]=f2b(v3.z); p1[7]=f2b(v3.w);
    }
    *(u16x8*)&hsb[r][qp * 16] = p0;
    *(u16x8*)&hsb[r][qp * 16 + 8] = p1;
  }
  __syncthreads();

  AB bfr[2][4];
#pragma unroll
  for (int ks = 0; ks < 2; ++ks)
#pragma unroll
    for (int ct = 0; ct < 4; ++ct) {
      int c = c0 + w * 64 + ct * 16 + (lane & 15);
      int kb = ks * 32 + (lane >> 4) * 8;
      if (c < KTOT) bfr[ks][ct].u = *(const u16x8*)(w2qT + (size_t)c * 64 + kb);
      else bfr[ks][ct].u = (u16x8){0,0,0,0,0,0,0,0};
    }
  AB afr[2][4];
#pragma unroll
  for (int ks = 0; ks < 2; ++ks)
#pragma unroll
    for (int rt = 0; rt < 4; ++rt)
      afr[ks][rt].u = *(const u16x8*)&hsb[rt * 16 + (lane & 15)][ks * 32 + (lane >> 4) * 8];

  f32x4 acc[4][4];
#pragma unroll
  for (int rt = 0; rt < 4; ++rt)
#pragma unroll
    for (int ct = 0; ct < 4; ++ct) acc[rt][ct] = (f32x4){0.f, 0.f, 0.f, 0.f};

#pragma unroll
  for (int ks = 0; ks < 2; ++ks)
#pragma unroll
    for (int ct = 0; ct < 4; ++ct)
#pragma unroll
      for (int rt = 0; rt < 4; ++rt)
        acc[rt][ct] = __builtin_amdgcn_mfma_f32_16x16x32_bf16(afr[ks][rt].b, bfr[ks][ct].b, acc[rt][ct], 0, 0, 0);

#pragma unroll
  for (int rt = 0; rt < 4; ++rt)
#pragma unroll
    for (int ct = 0; ct < 4; ++ct) {
      int lcol = w * 64 + ct * 16 + (lane & 15);
      int lrow0 = rt * 16 + (lane >> 4) * 4;
#pragma unroll
      for (int r = 0; r < 4; ++r) outs[lrow0 + r][lcol] = f2b(acc[rt][ct][r]);
    }
  __syncthreads();

  {
    int r2 = t & 63, seg = t >> 6;
    int row = row0 + r2;
    if (row < N_NODES) {
#pragma unroll
      for (int i = 0; i < 8; ++i) {
        int c = seg * 64 + i * 8;
        int gc = c0 + c;
        if (gc < KTOT)
          *(u16x8*)(G + (size_t)row * GSTRIDE + gc) = *(const u16x8*)&outs[r2][c];
      }
    }
  }
}

// -------------------- msg3: CSR-by-src, G row staged in LDS --------------------
__global__ __launch_bounds__(256) void k_msg3(const int* __restrict__ starts,
                                              const int* __restrict__ eidx,
                                              const int* __restrict__ dst,
                                              const float* __restrict__ r1,
                                              const u16* __restrict__ G,
                                              float* __restrict__ agg) {
  __shared__ u16 grow[128 * 64];
  __shared__ float gbias[64];
  __shared__ float r1e[128];
  __shared__ float part[4][64];
  int s = blockIdx.x;
  int e0 = starts[s], e1 = starts[s + 1];
  if (e0 >= e1) return;
  int t = threadIdx.x, w = t >> 6, l = t & 63;

  const u16* Gs = G + (size_t)s * GSTRIDE;
#pragma unroll
  for (int i = 0; i < 4; ++i)
    *(u16x8*)(grow + t * 8 + i * 2048) = *(const u16x8*)(Gs + t * 8 + i * 2048);
  if (t < 64) gbias[t] = b2f(Gs[8192 + t]);
  __syncthreads();

  for (int ei = e0; ei < e1; ++ei) {
    int e = eidx[ei];
    if (t < 128) r1e[t] = r1[(size_t)e * HID + t];
    __syncthreads();
    float acc = 0.f;
    const u16* gw = grow + w * 32 * 64 + l;
#pragma unroll 8
    for (int kap = 0; kap < 32; ++kap)
      acc += r1e[w * 32 + kap] * b2f(gw[kap * 64]);
    part[w][l] = acc;
    __syncthreads();
    if (t < 64) {
      float v = part[0][l] + part[1][l] + part[2][l] + part[3][l] + gbias[l];
      atomicAdd(&agg[(size_t)dst[e] * 64 + l], v);
    }
    __syncthreads();
  }
}

// -------------------- fallback: fused msg (VALU; r1 recomputed in-block) ----------
__global__ __launch_bounds__(256) void k_msgv(const int* __restrict__ src,
                                              const int* __restrict__ dst,
                                              const float* __restrict__ h,
                                              const float* __restrict__ ea,
                                              const float* __restrict__ w1,
                                              const float* __restrict__ b1,
                                              const float* __restrict__ w2,
                                              const float* __restrict__ b2,
                                              float* __restrict__ agg) {
  __shared__ float hs[64][68];
  __shared__ float r1sv[64][132];
  __shared__ float w1s[EDGE_FEAT][HID];
  __shared__ float b1s[HID];
  __shared__ float eas[64][EDGE_FEAT];
  __shared__ int dsts[64];

  int bm = blockIdx.x, ky = blockIdx.y;
  int t = threadIdx.x;
  int wave = t >> 6, lane = t & 63;

  if (t < HID) b1s[t] = b1[t];
  for (int i = t; i < EDGE_FEAT * HID; i += 256) w1s[i / HID][i % HID] = w1[i];
  {
    int r = t >> 2, qp = t & 3;
    int e = bm * 64 + r;
    if (t < 64) dsts[t] = (bm * 64 + t < N_EDGES) ? dst[bm * 64 + t] : -1;
    if (e < N_EDGES) {
      int s = src[e];
#pragma unroll
      for (int i = 0; i < 16; ++i) hs[r][qp * 16 + i] = h[(size_t)s * 64 + qp * 16 + i];
      if (qp == 0)
#pragma unroll
        for (int k = 0; k < EDGE_FEAT; ++k) eas[r][k] = ea[(size_t)e * EDGE_FEAT + k];
    } else {
#pragma unroll
      for (int i = 0; i < 16; ++i) hs[r][qp * 16 + i] = 0.f;
      if (qp == 0)
#pragma unroll
        for (int k = 0; k < EDGE_FEAT; ++k) eas[r][k] = 0.f;
    }
  }
  __syncthreads();

  for (int idx = t; idx < 64 * HID; idx += 256) {
    int rr = idx >> 7, c = idx & 127;
    float acc = b1s[c];
#pragma unroll
    for (int k = 0; k < EDGE_FEAT; ++k) acc += eas[rr][k] * w1s[k][c];
    r1sv[rr][c] = fmaxf(acc, 0.f);
  }
  if (t < 64) r1sv[t][128] = 1.0f;
  __syncthreads();

  int row0 = wave * 16 + (lane >> 4) * 4;
  int colb = lane & 15;

  float acc[4][4];
#pragma unroll
  for (int ct = 0; ct < 4; ++ct)
#pragma unroll
    for (int r = 0; r < 4; ++r) acc[ct][r] = 0.f;

  int k0 = ky * KCHUNK, k1 = k0 + KCHUNK;
  for (int kp = k0; kp < k1; ++kp) {
    int kap = kp >> 6, ii = kp & 63;
    const float* Bp = (kp < 8192) ? (w2 + (size_t)kp * 64)
                                  : (b2 + (size_t)(kp - 8192) * 64);
    float bv[4];
#pragma unroll
    for (int ct = 0; ct < 4; ++ct) bv[ct] = Bp[ct * 16 + colb];
#pragma unroll
    for (int r = 0; r < 4; ++r) {
      float a = r1sv[row0 + r][kap] * hs[row0 + r][ii];
#pragma unroll
      for (int ct = 0; ct < 4; ++ct) acc[ct][r] += a * bv[ct];
    }
  }

#pragma unroll
  for (int ct = 0; ct < 4; ++ct) {
    int col = ct * 16 + colb;
#pragma unroll
    for (int r = 0; r < 4; ++r) {
      int dd = dsts[row0 + r];
      if (dd >= 0) atomicAdd(&agg[(size_t)dd * 64 + col], acc[ct][r]);
    }
  }
}

// ---------- GRU step, 16 nodes/block, weights in VGPRs; zeroes agg; optional out-write ----------
__global__ __launch_bounds__(256) void k_gru2(const float* __restrict__ agg_in, const float* __restrict__ deg,
                                              const float* __restrict__ conv_b,
                                              const float* __restrict__ wih, const float* __restrict__ whh,
                                              const float* __restrict__ bih, const float* __restrict__ bhh,
                                              float* __restrict__ h, float* __restrict__ agg_clr,
                                              float* __restrict__ outp) {
  __shared__ float ms[GNB][64], hsn[GNB][64];
  __shared__ float gis[GNB][192], ghs[GNB][192];
  int n0 = blockIdx.x * GNB;
  int t = threadIdx.x;

  for (int idx = t; idx < GNB * 64; idx += 256) {
    int r = idx >> 6, c = idx & 63;
    int n = n0 + r;
    if (n < N_NODES) {
      float dg = fmaxf(deg[n], 1.0f);
      ms[r][c] = fmaxf(agg_in[(size_t)n * 64 + c] / dg + conv_b[c], 0.f);
      hsn[r][c] = h[(size_t)n * 64 + c];
      agg_clr[(size_t)n * 64 + c] = 0.f;
    } else { ms[r][c] = 0.f; hsn[r][c] = 0.f; }
  }
  __syncthreads();

  if (t < 192) {
    f32x4 wr[16];
    const f32x4* wp = (const f32x4*)(wih + (size_t)t * 64);
#pragma unroll
    for (int i = 0; i < 16; ++i) wr[i] = wp[i];
    float bi = bih[t];
    for (int n = 0; n < GNB; ++n) {
      float acc = bi;
#pragma unroll
      for (int i = 0; i < 16; ++i) {
        f32x4 v = wr[i];
        acc += ms[n][4*i] * v.x + ms[n][4*i+1] * v.y + ms[n][4*i+2] * v.z + ms[n][4*i+3] * v.w;
      }
      gis[n][t] = acc;
    }
    const f32x4* hp = (const f32x4*)(whh + (size_t)t * 64);
#pragma unroll
    for (int i = 0; i < 16; ++i) wr[i] = hp[i];
    float bh = bhh[t];
    for (int n = 0; n < GNB; ++n) {
      float acc = bh;
#pragma unroll
      for (int i = 0; i < 16; ++i) {
        f32x4 v = wr[i];
        acc += hsn[n][4*i] * v.x + hsn[n][4*i+1] * v.y + hsn[n][4*i+2] * v.z + hsn[n][4*i+3] * v.w;
      }
      ghs[n][t] = acc;
    }
  }
  __syncthreads();

  for (int idx = t; idx < GNB * 64; idx += 256) {
    int rr = idx >> 6, c = idx & 63;
    int n = n0 + rr;
    if (n < N_NODES) {
      float r = sigf(gis[rr][c] + ghs[rr][c]);
      float z = sigf(gis[rr][64 + c] + ghs[rr][64 + c]);
      float nn = tanhf(gis[rr][128 + c] + r * ghs[rr][128 + c]);
      float hv = (1.f - z) * nn + z * hsn[rr][c];
      h[(size_t)n * 64 + c] = hv;
      if (outp) outp[B_GRAPHS * 128 + (size_t)n * 64 + c] = hv;
    }
  }
}

// -------------------- fused Set2Set: feat cached in LDS, 3 steps in-kernel ----------
__global__ __launch_bounds__(256) void k_s2s(const float* __restrict__ wih, const float* __restrict__ whh,
                                             const float* __restrict__ bih, const float* __restrict__ bhh,
                                             const float* __restrict__ feat, const int* __restrict__ start,
                                             float* __restrict__ ev, float* __restrict__ outq) {
  __shared__ float fl[S2SCAP][65];
  __shared__ float al[S2SCAP];
  __shared__ float qs[128], hhs[64], ccs[64], gates[256], part[4][64];
  int g = blockIdx.x, t = threadIdx.x, w = t >> 6, l = t & 63;
  int s0 = start[g], s1 = start[g + 1];
  int cnt = s1 - s0;
  bool fits = (cnt <= S2SCAP);

  if (fits) {
    for (int idx = t; idx < cnt * 16; idx += 256) {
      int n = idx >> 4, q = idx & 15;
      *(f32x4*)&fl[n][q * 4] = *(const f32x4*)(feat + (size_t)(s0 + n) * 64 + q * 4);
    }
  }
  if (t < 128) qs[t] = 0.f;
  if (t < 64) { hhs[t] = 0.f; ccs[t] = 0.f; }
  __syncthreads();

  for (int step = 0; step < 3; ++step) {
    // ---- LSTM gates ----
    {
      float acc = bih[t] + bhh[t];
      const f32x4* wr = (const f32x4*)(wih + (size_t)t * 128);
#pragma unroll
      for (int i = 0; i < 32; ++i) {
        f32x4 v = wr[i];
        acc += qs[4 * i] * v.x + qs[4 * i + 1] * v.y + qs[4 * i + 2] * v.z + qs[4 * i + 3] * v.w;
      }
      const f32x4* hr = (const f32x4*)(whh + (size_t)t * 64);
#pragma unroll
      for (int i = 0; i < 16; ++i) {
        f32x4 v = hr[i];
        acc += hhs[4 * i] * v.x + hhs[4 * i + 1] * v.y + hhs[4 * i + 2] * v.z + hhs[4 * i + 3] * v.w;
      }
      gates[t] = acc;
    }
    __syncthreads();
    if (t < 64) {
      float c_new = sigf(gates[64 + t]) * ccs[t] + sigf(gates[t]) * tanhf(gates[128 + t]);
      hhs[t] = sigf(gates[192 + t]) * tanhf(c_new);
      ccs[t] = c_new;
      qs[t] = hhs[t];
    }
    __syncthreads();

    // ---- attention scores (thread per node) ----
    float mymax = -1e30f;
    if (fits) {
      for (int n = t; n < cnt; n += 256) {
        float acc = 0.f;
#pragma unroll 16
        for (int c = 0; c < 64; ++c) acc += fl[n][c] * hhs[c];
        al[n] = acc;
        mymax = fmaxf(mymax, acc);
      }
    } else {
      for (int n = t; n < cnt; n += 256) {
        float acc = 0.f;
        for (int c = 0; c < 64; ++c) acc += feat[(size_t)(s0 + n) * 64 + c] * hhs[c];
        ev[s0 + n] = acc;
        mymax = fmaxf(mymax, acc);
      }
    }
    gates[t] = mymax; __syncthreads();
    for (int off = 128; off; off >>= 1) { if (t < off) gates[t] = fmaxf(gates[t], gates[t + off]); __syncthreads(); }
    float emax = gates[0];
    __syncthreads();

    // ---- denominator + normalized weights ----
    float sd = 0.f;
    if (fits) {
      for (int n = t; n < cnt; n += 256) { float e = expf(al[n] - emax); al[n] = e; sd += e; }
    } else {
      for (int n = t; n < cnt; n += 256) sd += expf(ev[s0 + n] - emax);
    }
    gates[t] = sd; __syncthreads();
    for (int off = 128; off; off >>= 1) { if (t < off) gates[t] += gates[t + off]; __syncthreads(); }
    float den = gates[0];
    __syncthreads();

    // ---- weighted pool ----
    float pacc = 0.f;
    if (fits) {
      for (int n = w; n < cnt; n += 4) pacc += al[n] * fl[n][l];
      pacc /= den;
    } else {
      for (int n = w; n < cnt; n += 4) {
        float a = expf(ev[s0 + n] - emax) / den;
        pacc += a * feat[(size_t)(s0 + n) * 64 + l];
      }
    }
    part[w][l] = pacc; __syncthreads();
    if (t < 64) qs[64 + t] = part[0][t] + part[1][t] + part[2][t] + part[3][t];
    __syncthreads();
  }
  if (t < 128) outq[g * 128 + t] = qs[t];
}

extern "C" void kernel_launch(void* const* d_in, const int* in_sizes, int n_in,
                              void* d_out, int out_size, void* d_ws, size_t ws_size,
                              hipStream_t stream) {
  (void)in_sizes; (void)n_in; (void)out_size;
  const float* x        = (const float*)d_in[0];
  const int*   ei       = (const int*)d_in[1];
  const int*   batch    = (const int*)d_in[2];
  const float* ea       = (const float*)d_in[3];
  const float* lin0_w   = (const float*)d_in[4];
  const float* lin0_b   = (const float*)d_in[5];
  const float* nn_w1    = (const float*)d_in[6];
  const float* nn_b1    = (const float*)d_in[7];
  const float* nn_w2    = (const float*)d_in[8];
  const float* nn_b2    = (const float*)d_in[9];
  const float* conv_b   = (const float*)d_in[10];
  const float* gru_w_ih = (const float*)d_in[11];
  const float* gru_w_hh = (const float*)d_in[12];
  const float* gru_b_ih = (const float*)d_in[13];
  const float* gru_b_hh = (const float*)d_in[14];
  const float* lstm_w_ih= (const float*)d_in[15];
  const float* lstm_w_hh= (const float*)d_in[16];
  const float* lstm_b_ih= (const float*)d_in[17];
  const float* lstm_b_hh= (const float*)d_in[18];
  const int* srcp = ei;
  const int* dstp = ei + N_EDGES;

  char* ws = (char*)d_ws;
  size_t off = 0;
  auto alloc = [&](size_t bytes) { void* p = ws + off; off += (bytes + 255) & ~(size_t)255; return p; };
  float* h     = (float*)alloc((size_t)N_NODES * 64 * 4);
  float* agg   = (float*)alloc((size_t)N_NODES * 64 * 4);
  float* deg   = (float*)alloc((size_t)N_NODES * 4);
  float* ev    = (float*)alloc((size_t)N_NODES * 4);
  int*   startv= (int*)alloc(65 * 4);
  int*   cnt   = (int*)alloc((size_t)N_NODES * 4);
  int*   starts= (int*)alloc((size_t)(N_NODES + 1) * 4);
  int*   ptr2  = (int*)alloc((size_t)N_NODES * 4);
  int*   eidx  = (int*)alloc((size_t)N_EDGES * 4);
  float* r1    = (float*)alloc((size_t)N_EDGES * HID * 4);
  u16*   w2qT  = (u16*)alloc((size_t)KTOT * 64 * 2);
  u16*   G     = (u16*)alloc((size_t)N_NODES * GSTRIDE * 2);
  bool useG = (ws_size >= off);

  hipMemsetAsync(deg, 0, (size_t)N_NODES * 4, stream);
  hipMemsetAsync(agg, 0, (size_t)N_NODES * 64 * 4, stream);

  k_lin0<<<(N_NODES + 3) / 4, 256, 0, stream>>>(x, lin0_w, lin0_b, h);
  k_bounds<<<1, 128, 0, stream>>>(batch, startv);

  if (useG) {
    hipMemsetAsync(cnt, 0, (size_t)N_NODES * 4, stream);
    k_degcnt<<<(N_EDGES + 255) / 256, 256, 0, stream>>>(srcp, dstp, deg, cnt);
    k_scan<<<1, 256, 0, stream>>>(cnt, starts, ptr2);
    k_place<<<(N_EDGES + 255) / 256, 256, 0, stream>>>(srcp, ptr2, eidx);
    k_r1b<<<N_EDGES / 2, 256, 0, stream>>>(ea, nn_w1, nn_b1, r1);
    k_w2pT<<<129, 256, 0, stream>>>(nn_w2, nn_b2, w2qT);
    for (int it = 0; it < 3; ++it) {
      k_Gm<<<dim3((N_NODES + 63) / 64, (KTOT + 255) / 256), 256, 0, stream>>>(h, w2qT, G);
      k_msg3<<<N_NODES, 256, 0, stream>>>(starts, eidx, dstp, r1, G, agg);
      k_gru2<<<(N_NODES + GNB - 1) / GNB, 256, 0, stream>>>(agg, deg, conv_b, gru_w_ih, gru_w_hh,
                                                            gru_b_ih, gru_b_hh, h, agg,
                                                            (it == 2) ? (float*)d_out : nullptr);
    }
  } else {
    hipMemsetAsync(cnt, 0, (size_t)N_NODES * 4, stream);
    k_degcnt<<<(N_EDGES + 255) / 256, 256, 0, stream>>>(srcp, dstp, deg, cnt);
    for (int it = 0; it < 3; ++it) {
      k_msgv<<<dim3(313, KY_SPLIT), 256, 0, stream>>>(srcp, dstp, h, ea, nn_w1, nn_b1,
                                                      nn_w2, nn_b2, agg);
      k_gru2<<<(N_NODES + GNB - 1) / GNB, 256, 0, stream>>>(agg, deg, conv_b, gru_w_ih, gru_w_hh,
                                                            gru_b_ih, gru_b_hh, h, agg,
                                                            (it == 2) ? (float*)d_out : nullptr);
    }
  }

  k_s2s<<<B_GRAPHS, 256, 0, stream>>>(lstm_w_ih, lstm_w_hh, lstm_b_ih, lstm_b_hh,
                                      h, startv, ev, (float*)d_out);
}